// Round 8
// baseline (172.671 us; speedup 1.0000x reference)
//
#include <hip/hip_runtime.h>
#include <hip/hip_bf16.h>

// EdgeEncoder — fp32 inputs, algebraically folded attention:
//   k[i,j] = kbase[j] + W2k @ hid[i,j],   W2k = Wk @ W2
//   score  = q.kbase[j] + qw[i,hd].hid[i,j]
//   ctx    = sum_j attn*vbase[j] + W2v @ (sum_j attn*hid[i,j])
//
// R15 = R14 (68.8us) + staging of the LAST two in-stage load clusters.
// Model (validated by R13/R14 gains ~50cyc/load): kernel is bound by
// vmem load-latency chains (~340 loads/wave), not VALU issue. Remaining
// in-stage clusters: WQB (32 loads, S2) and W2VT (64 loads, S7).
//   wqA (WQB m8 0-7)  issued in S1 after feats loads
//   wqB (m8 8-15)+g4  issued top of S2
//   v2a (W2VT rows 0-31)  issued top of S6 after vb
//   v2b (rows 32-63)      issued top of S7; owA moved to MID-S7 (after
//   v2a dies) to keep peak VGPR ~236 < 256 cap.
// All consumption orders identical to R14 -> bit-identical output.
//
// ws layout (bytes):
//   [0,32K)     W2KB u32  [e][cw]   W2k bf16-pairs (16K used)
//   [32K,64K)   W2VT fp32 [e][ch]
//   [64K,96K)   WQB  u32  [c][mw]   Wq bf16-pairs
//   [96K,128K)  OWB  u32  [c][mw]   out_w
//   [128K,192K) PWB  u32  [c][mw]   proj_w
//   [192K,+2M)  KBt  u32  [s][cw][j]  kbase bf16-pairs, j fastest
//   [+2M,+4M)   VB   u32  [s][j][cw]  vbase, cw fastest

typedef unsigned int u32;
#define SCALE 0.17677669529663689f   // 1/sqrt(32)

__device__ __forceinline__ float bl(u32 u){ union{u32 x; float f;} c; c.x = u << 16; return c.f; }
__device__ __forceinline__ float bh(u32 u){ union{u32 x; float f;} c; c.x = u & 0xffff0000u; return c.f; }
__device__ __forceinline__ u32 pk(float a, float b){
  union{float f; u32 x;} ca, cb; ca.f = a; cb.f = b;
  u32 ua = (ca.x + 0x7fffu + ((ca.x >> 16) & 1u)) >> 16;   // RNE fp32->bf16
  u32 ub = (cb.x + 0x7fffu + ((cb.x >> 16) & 1u)) >> 16;
  return ua | (ub << 16);
}

#if __has_builtin(__builtin_amdgcn_fdot2_f32_bf16)
__device__ __forceinline__ float dot2b(u32 a, u32 b, float c){
  float d;
  asm("v_dot2_f32_bf16 %0, %1, %2, %3" : "=v"(d) : "v"(a), "v"(b), "v"(c));
  return d;
}
#else
__device__ __forceinline__ float dot2b(u32 a, u32 b, float c){
  c = fmaf(bl(a), bl(b), c);
  return fmaf(bh(a), bh(b), c);
}
#endif
__device__ __forceinline__ float dot8b(uint4 wv, uint4 fv, float acc){
  acc = dot2b(wv.x, fv.x, acc);
  acc = dot2b(wv.y, fv.y, acc);
  acc = dot2b(wv.z, fv.z, acc);
  acc = dot2b(wv.w, fv.w, acc);
  return acc;
}
__device__ __forceinline__ void wsync(){
  __builtin_amdgcn_s_waitcnt(0xC07F);   // lgkmcnt(0)
  __builtin_amdgcn_wave_barrier();
}

// ---------------- kernel 1: setup (unchanged) -------------------------------
__global__ __launch_bounds__(256, 2) void ee_setup(
    const float* __restrict__ nf, const float* __restrict__ b2,
    const float* __restrict__ ipw, const float* __restrict__ ipb,
    const float* __restrict__ w2,
    const float* __restrict__ ow, const float* __restrict__ pw,
    u32* __restrict__ W2KB, float* __restrict__ W2VT,
    u32* __restrict__ WQB, u32* __restrict__ OWB, u32* __restrict__ PWB,
    u32* __restrict__ KBt, u32* __restrict__ VB)
{
  const int tid = threadIdx.x, b = blockIdx.x;
  const int cg = tid >> 6, l = tid & 63;
  const float2* ipw2 = (const float2*)ipw;
  const float2* ow2  = (const float2*)ow;
  const float2* pw2  = (const float2*)pw;

  if (b >= 544) {              // ---- weight packing, fully coalesced ----
    for (int k = 0; k < 16; ++k) {
      int i = (b - 544) * 4096 + k * 256 + tid;    // 0..32767
      if (i < 8192)       { float2 f = ipw2[i];        WQB[i]        = pk(f.x, f.y); }
      else if (i < 16384) { float2 f = ow2[i - 8192];  OWB[i - 8192] = pk(f.x, f.y); }
      else                { float2 f = pw2[i - 16384]; PWB[i - 16384]= pk(f.x, f.y); }
    }
    return;
  }
  if (b >= 512) {              // ---- W2 folds: W2x[ch][e] = Wk/Wv @ W2 ----
    int t = (b - 512) * 4 + cg;
    int kv = t & 1, e = t >> 1;
    int c0 = 2 * l;
    const float4* rp = (const float4*)ipw + (size_t)(128 + kv * 128 + c0) * 32;
    const float* w2e = w2 + __builtin_amdgcn_readfirstlane(e);
    float a0 = 0.f, a1 = 0.f;
    #pragma unroll 8
    for (int c4 = 0; c4 < 32; ++c4) {
      float4 wa = rp[c4], wb = rp[32 + c4];
      float x0 = w2e[(4 * c4 + 0) * 64];
      float x1 = w2e[(4 * c4 + 1) * 64];
      float x2 = w2e[(4 * c4 + 2) * 64];
      float x3 = w2e[(4 * c4 + 3) * 64];
      a0 = fmaf(wa.x, x0, a0); a0 = fmaf(wa.y, x1, a0);
      a0 = fmaf(wa.z, x2, a0); a0 = fmaf(wa.w, x3, a0);
      a1 = fmaf(wb.x, x0, a1); a1 = fmaf(wb.y, x1, a1);
      a1 = fmaf(wb.z, x2, a1); a1 = fmaf(wb.w, x3, a1);
    }
    if (kv) ((float2*)W2VT)[e * 64 + l] = make_float2(a0, a1);
    else    W2KB[e * 64 + l] = pk(a0, a1);
    return;
  }

  const int s = b >> 2, kv = (b >> 1) & 1, hlf = b & 1;
  __shared__ __align__(16) u32 fbS[64][68];
  __shared__ u32 vtS[64][33];
  const float2* nf2 = (const float2*)nf;
  const float2* b22 = (const float2*)b2;

  for (int idx = tid; idx < 4096; idx += 256) {
    int j = idx >> 6, mw = idx & 63;
    float2 f = nf2[((s << 6) + j) * 64 + mw];
    float2 bb = b22[mw];
    fbS[j][mw] = pk(f.x + bb.x, f.y + bb.y);
  }
  __syncthreads();

  uint4 fr[16];
  {
    const uint4* frow = (const uint4*)&fbS[l][0];
    #pragma unroll
    for (int k = 0; k < 16; ++k) fr[k] = frow[k];
  }
  #pragma unroll 1
  for (int p = 0; p < 8; ++p) {
    int c0 = hlf * 64 + cg * 16 + 2 * p;
    int r0 = 128 + kv * 128 + c0;
    const float4* w0 = (const float4*)ipw +
                       (size_t)__builtin_amdgcn_readfirstlane(r0) * 32;
    const float4* w1r = w0 + 32;
    float a0 = ipb[r0], a1 = ipb[r0 + 1];
    #pragma unroll
    for (int k = 0; k < 16; ++k) {
      uint4 F = fr[k];
      float4 wa = w0[2 * k],  wb = w0[2 * k + 1];
      float4 xa = w1r[2 * k], xb = w1r[2 * k + 1];
      float e0 = bl(F.x), e1 = bh(F.x), e2 = bl(F.y), e3 = bh(F.y);
      float e4 = bl(F.z), e5 = bh(F.z), e6 = bl(F.w), e7 = bh(F.w);
      a0 = fmaf(e0, wa.x, a0); a0 = fmaf(e1, wa.y, a0);
      a0 = fmaf(e2, wa.z, a0); a0 = fmaf(e3, wa.w, a0);
      a0 = fmaf(e4, wb.x, a0); a0 = fmaf(e5, wb.y, a0);
      a0 = fmaf(e6, wb.z, a0); a0 = fmaf(e7, wb.w, a0);
      a1 = fmaf(e0, xa.x, a1); a1 = fmaf(e1, xa.y, a1);
      a1 = fmaf(e2, xa.z, a1); a1 = fmaf(e3, xa.w, a1);
      a1 = fmaf(e4, xb.x, a1); a1 = fmaf(e5, xb.y, a1);
      a1 = fmaf(e6, xb.z, a1); a1 = fmaf(e7, xb.w, a1);
    }
    u32 v = pk(a0, a1);
    int cw = hlf * 32 + cg * 8 + p;
    if (kv == 0) KBt[(((s << 6) + cw) << 6) + l] = v;
    else         vtS[l][cg * 8 + p] = v;
  }
  if (kv == 1) {
    __syncthreads();
    int r = tid >> 2, cb = (tid & 3) * 8;
    #pragma unroll
    for (int k = 0; k < 8; ++k)
      VB[(((s << 6) + r) << 6) + hlf * 32 + cb + k] = vtS[r][cb + k];
  }
}

// ---------------- kernel 2: Q=4, wave-synchronous, fully staged -------------
__global__ __launch_bounds__(256, 2) void ee_main(
    const float* __restrict__ nf, const float* __restrict__ pos,
    const float* __restrict__ w1, const float* __restrict__ b1,
    const float* __restrict__ ipb,
    const float* __restrict__ ob, const float* __restrict__ pb,
    const u32* __restrict__ W2KB, const float* __restrict__ W2VT,
    const u32* __restrict__ WQB, const u32* __restrict__ OWB,
    const u32* __restrict__ PWB,
    const u32* __restrict__ KBt, const u32* __restrict__ VB,
    float* __restrict__ outp)
{
  __shared__ __align__(16) float pxS[64], pyS[64], w1xS[64], w1yS[64], b1S[64];
  __shared__ __align__(16) u32 fqSu[4][4][68];       // feats bf16 pairs
  __shared__ __align__(16) u32 qSu [4][4][68];       // q -> ctx, bf16 pairs
  __shared__ __align__(16) float qwhS[4][4][4][68];  // qw (S4/S5) | wh | ao
  __shared__ __align__(16) float atS[4][4][4][68];   // at [w][t][hd][j]

  const int tid = threadIdx.x;
  const int s = blockIdx.x >> 2, qt = blockIdx.x & 3;
  const int w = tid >> 6, l = tid & 63;
  const int c0 = 2 * l;

  if (tid < 64) {
    float2 p = ((const float2*)pos)[(s << 6) + tid];
    pxS[tid] = p.x; pyS[tid] = p.y;
    float2 wv = ((const float2*)w1)[tid];
    w1xS[tid] = wv.x; w1yS[tid] = wv.y;
    b1S[tid] = b1[tid];
  }
  __syncthreads();
  // ---- no block barriers past here ----

  int il[4], ig[4];
  #pragma unroll
  for (int t = 0; t < 4; ++t) { il[t] = qt * 16 + 4 * w + t; ig[t] = (s << 6) + il[t]; }

  const uint4* W4q = (const uint4*)WQB;
  const uint4* W4o = (const uint4*)OWB;
  const uint4* W4p = (const uint4*)PWB;

  // S1: feats loads, then wqA batch issue (feats oldest in FIFO), pk -> LDS
  float2 fql[4];
  #pragma unroll
  for (int t = 0; t < 4; ++t) fql[t] = ((const float2*)nf)[ig[t] * 64 + l];
  uint4 wqA[16];
  #pragma unroll
  for (int m8 = 0; m8 < 8; ++m8) {
    wqA[2 * m8]     = W4q[c0 * 16 + m8];
    wqA[2 * m8 + 1] = W4q[(c0 + 1) * 16 + m8];
  }
  #pragma unroll
  for (int t = 0; t < 4; ++t) fqSu[w][t][l] = pk(fql[t].x, fql[t].y);
  wsync();

  // S2: q = Wq @ feats + bq  (wqA staged; wqB + g4 issued here)
  uint4 wqB[16];
  #pragma unroll
  for (int m8 = 8; m8 < 16; ++m8) {
    wqB[2 * (m8 - 8)]     = W4q[c0 * 16 + m8];
    wqB[2 * (m8 - 8) + 1] = W4q[(c0 + 1) * 16 + m8];
  }
  uint4 g4[16];
  {
    const uint4* G4k = (const uint4*)W2KB + l * 16;
    #pragma unroll
    for (int i = 0; i < 16; ++i) g4[i] = G4k[i];
  }
  {
    float2 bq = ((const float2*)ipb)[l];
    float a0[4], a1[4];
    #pragma unroll
    for (int t = 0; t < 4; ++t) { a0[t] = bq.x; a1[t] = bq.y; }
    #pragma unroll
    for (int m8 = 0; m8 < 8; ++m8) {
      #pragma unroll
      for (int t = 0; t < 4; ++t) {
        uint4 fp = *(const uint4*)&fqSu[w][t][4 * m8];
        a0[t] = dot8b(wqA[2 * m8],     fp, a0[t]);
        a1[t] = dot8b(wqA[2 * m8 + 1], fp, a1[t]);
      }
    }
    #pragma unroll
    for (int m8 = 8; m8 < 16; ++m8) {
      #pragma unroll
      for (int t = 0; t < 4; ++t) {
        uint4 fp = *(const uint4*)&fqSu[w][t][4 * m8];
        a0[t] = dot8b(wqB[2 * (m8 - 8)],     fp, a0[t]);
        a1[t] = dot8b(wqB[2 * (m8 - 8) + 1], fp, a1[t]);
      }
    }
    #pragma unroll
    for (int t = 0; t < 4; ++t) qSu[w][t][l] = pk(a0[t], a1[t]);
  }
  wsync();

  // S4: qw[t][hd][e=l] = q_hd . W2k[:,e]_hd  (g4 staged; kb issued here)
  u32 kb[64];
  {
    const u32* kbp = KBt + (s << 12);
    #pragma unroll
    for (int j = 0; j < 64; ++j) kb[j] = kbp[(j << 6) + l];
  }
  {
    #pragma unroll
    for (int hd = 0; hd < 4; ++hd) {
      float acc[4] = {0.f, 0.f, 0.f, 0.f};
      #pragma unroll
      for (int dq2 = 0; dq2 < 4; ++dq2) {
        uint4 g = g4[hd * 4 + dq2];
        #pragma unroll
        for (int t = 0; t < 4; ++t) {
          uint4 qp = *(const uint4*)&qSu[w][t][hd * 16 + 4 * dq2];
          acc[t] = dot2b(g.x, qp.x, acc[t]);
          acc[t] = dot2b(g.y, qp.y, acc[t]);
          acc[t] = dot2b(g.z, qp.z, acc[t]);
          acc[t] = dot2b(g.w, qp.w, acc[t]);
        }
      }
      #pragma unroll
      for (int t = 0; t < 4; ++t) qwhS[w][t][hd][l] = acc[t];
    }
  }
  wsync();

  // S5: scores + softmax (lane = j; kb in registers, R11 order)
  float at[4][4];        // [t][hd]
  float pix[4], piy[4];
  {
    float pjx = pxS[l], pjy = pyS[l];
    float rx[4], ry[4];
    #pragma unroll
    for (int t = 0; t < 4; ++t) {
      pix[t] = pxS[il[t]]; piy[t] = pyS[il[t]];      // broadcast reads
      rx[t] = pjx - pix[t]; ry[t] = pjy - piy[t];
    }
    float sc[4][4];
    #pragma unroll
    for (int t = 0; t < 4; ++t)
      #pragma unroll
      for (int hd = 0; hd < 4; ++hd) sc[t][hd] = 0.f;

    #pragma unroll
    for (int m2 = 0; m2 < 32; ++m2) {
      u32 u0 = kb[2 * m2], u1 = kb[2 * m2 + 1];
      const int hd = m2 >> 3;
      #pragma unroll
      for (int t = 0; t < 4; ++t) {
        uint2 qp = *(const uint2*)&qSu[w][t][2 * m2];
        sc[t][hd] = dot2b(u0, qp.x, sc[t][hd]);
        sc[t][hd] = dot2b(u1, qp.y, sc[t][hd]);
      }
    }
    #pragma unroll 2
    for (int eb = 0; eb < 8; ++eb) {
      float4 wx0 = *(const float4*)&w1xS[8 * eb];
      float4 wx1 = *(const float4*)&w1xS[8 * eb + 4];
      float4 wy0 = *(const float4*)&w1yS[8 * eb];
      float4 wy1 = *(const float4*)&w1yS[8 * eb + 4];
      float4 bb0 = *(const float4*)&b1S[8 * eb];
      float4 bb1 = *(const float4*)&b1S[8 * eb + 4];
      #pragma unroll
      for (int t = 0; t < 4; ++t) {
        float h0 = fmaxf(0.f, fmaf(rx[t], wx0.x, fmaf(ry[t], wy0.x, bb0.x)));
        float h1 = fmaxf(0.f, fmaf(rx[t], wx0.y, fmaf(ry[t], wy0.y, bb0.y)));
        float h2 = fmaxf(0.f, fmaf(rx[t], wx0.z, fmaf(ry[t], wy0.z, bb0.z)));
        float h3 = fmaxf(0.f, fmaf(rx[t], wx0.w, fmaf(ry[t], wy0.w, bb0.w)));
        float h4 = fmaxf(0.f, fmaf(rx[t], wx1.x, fmaf(ry[t], wy1.x, bb1.x)));
        float h5 = fmaxf(0.f, fmaf(rx[t], wx1.y, fmaf(ry[t], wy1.y, bb1.y)));
        float h6 = fmaxf(0.f, fmaf(rx[t], wx1.z, fmaf(ry[t], wy1.z, bb1.z)));
        float h7 = fmaxf(0.f, fmaf(rx[t], wx1.w, fmaf(ry[t], wy1.w, bb1.w)));
        #pragma unroll
        for (int hd = 0; hd < 4; ++hd) {
          float4 q0 = *(const float4*)&qwhS[w][t][hd][8 * eb];
          float4 q1 = *(const float4*)&qwhS[w][t][hd][8 * eb + 4];
          float a = sc[t][hd];
          a = fmaf(q0.x, h0, a); a = fmaf(q0.y, h1, a);
          a = fmaf(q0.z, h2, a); a = fmaf(q0.w, h3, a);
          a = fmaf(q1.x, h4, a); a = fmaf(q1.y, h5, a);
          a = fmaf(q1.z, h6, a); a = fmaf(q1.w, h7, a);
          sc[t][hd] = a;
        }
      }
    }
    #pragma unroll
    for (int t = 0; t < 4; ++t) {
      #pragma unroll
      for (int hd = 0; hd < 4; ++hd) {
        float v = sc[t][hd] * SCALE;
        float m = v;
        #pragma unroll
        for (int off = 32; off > 0; off >>= 1) m = fmaxf(m, __shfl_xor(m, off));
        float p = __expf(v - m);
        float su = p;
        #pragma unroll
        for (int off = 32; off > 0; off >>= 1) su += __shfl_xor(su, off);
#if __has_builtin(__builtin_amdgcn_rcpf)
        at[t][hd] = p * __builtin_amdgcn_rcpf(su);
#else
        at[t][hd] = p / su;
#endif
        atS[w][t][hd][l] = at[t][hd];
      }
    }
  }
  wsync();

  // S6: wh[t][hd][e=l] = sum_j at*hid  (vb + v2a issued here)
  u32 vb[64];
  {
    const u32* vbp = VB + (s << 12);
    #pragma unroll
    for (int j = 0; j < 64; ++j) vb[j] = vbp[(j << 6) + l];
  }
  float2 v2a[32];
  {
    const float2* V2 = (const float2*)W2VT;
    #pragma unroll
    for (int i = 0; i < 32; ++i) v2a[i] = V2[(i << 6) + l];
  }
  {
    float wx = w1xS[l], wy = w1yS[l], bb = b1S[l];
    float wh[4][4];
    #pragma unroll
    for (int t = 0; t < 4; ++t)
      #pragma unroll
      for (int hd = 0; hd < 4; ++hd) wh[t][hd] = 0.f;
    #pragma unroll 4
    for (int j4 = 0; j4 < 16; ++j4) {
      float4 px = *(const float4*)&pxS[4 * j4];
      float4 py = *(const float4*)&pyS[4 * j4];
      #pragma unroll
      for (int t = 0; t < 4; ++t) {
        float4 a0v = *(const float4*)&atS[w][t][0][4 * j4];
        float4 a1v = *(const float4*)&atS[w][t][1][4 * j4];
        float4 a2v = *(const float4*)&atS[w][t][2][4 * j4];
        float4 a3v = *(const float4*)&atS[w][t][3][4 * j4];
        float h;
        h = fmaxf(0.f, fmaf(px.x - pix[t], wx, fmaf(py.x - piy[t], wy, bb)));
        wh[t][0] = fmaf(a0v.x, h, wh[t][0]); wh[t][1] = fmaf(a1v.x, h, wh[t][1]);
        wh[t][2] = fmaf(a2v.x, h, wh[t][2]); wh[t][3] = fmaf(a3v.x, h, wh[t][3]);
        h = fmaxf(0.f, fmaf(px.y - pix[t], wx, fmaf(py.y - piy[t], wy, bb)));
        wh[t][0] = fmaf(a0v.y, h, wh[t][0]); wh[t][1] = fmaf(a1v.y, h, wh[t][1]);
        wh[t][2] = fmaf(a2v.y, h, wh[t][2]); wh[t][3] = fmaf(a3v.y, h, wh[t][3]);
        h = fmaxf(0.f, fmaf(px.z - pix[t], wx, fmaf(py.z - piy[t], wy, bb)));
        wh[t][0] = fmaf(a0v.z, h, wh[t][0]); wh[t][1] = fmaf(a1v.z, h, wh[t][1]);
        wh[t][2] = fmaf(a2v.z, h, wh[t][2]); wh[t][3] = fmaf(a3v.z, h, wh[t][3]);
        h = fmaxf(0.f, fmaf(px.w - pix[t], wx, fmaf(py.w - piy[t], wy, bb)));
        wh[t][0] = fmaf(a0v.w, h, wh[t][0]); wh[t][1] = fmaf(a1v.w, h, wh[t][1]);
        wh[t][2] = fmaf(a2v.w, h, wh[t][2]); wh[t][3] = fmaf(a3v.w, h, wh[t][3]);
      }
    }
    #pragma unroll
    for (int t = 0; t < 4; ++t)
      #pragma unroll
      for (int hd = 0; hd < 4; ++hd) qwhS[w][t][hd][l] = wh[t][hd];
  }
  wsync();

  // S7: ctx (vb + v2a staged; v2b issued at top; owA issued MID-stage after
  // v2a dies to bound peak VGPR; FMA order identical to R14)
  float2 v2b[32];
  {
    const float2* V2 = (const float2*)W2VT;
    #pragma unroll
    for (int i = 0; i < 32; ++i) v2b[i] = V2[((32 + i) << 6) + l];
  }
  uint4 owA[16];
  {
    const int hd = l >> 4;
    float cx0[4] = {0,0,0,0}, cx1[4] = {0,0,0,0};
    #pragma unroll
    for (int n4 = 0; n4 < 8; ++n4) {             // rows 0..31 from v2a
      float2 g0 = v2a[4 * n4 + 0];
      float2 g1 = v2a[4 * n4 + 1];
      float2 g2 = v2a[4 * n4 + 2];
      float2 g3 = v2a[4 * n4 + 3];
      u32 v0 = vb[4 * n4 + 0];
      u32 v1 = vb[4 * n4 + 1];
      u32 v2 = vb[4 * n4 + 2];
      u32 v3 = vb[4 * n4 + 3];
      #pragma unroll
      for (int t = 0; t < 4; ++t) {
        float4 whv = *(const float4*)&qwhS[w][t][hd][4 * n4];
        float4 atv = *(const float4*)&atS[w][t][hd][4 * n4];
        float a0 = cx0[t], a1 = cx1[t];
        a0 = fmaf(whv.x, g0.x, a0); a1 = fmaf(whv.x, g0.y, a1);
        a0 = fmaf(atv.x, bl(v0), a0); a1 = fmaf(atv.x, bh(v0), a1);
        a0 = fmaf(whv.y, g1.x, a0); a1 = fmaf(whv.y, g1.y, a1);
        a0 = fmaf(atv.y, bl(v1), a0); a1 = fmaf(atv.y, bh(v1), a1);
        a0 = fmaf(whv.z, g2.x, a0); a1 = fmaf(whv.z, g2.y, a1);
        a0 = fmaf(atv.z, bl(v2), a0); a1 = fmaf(atv.z, bh(v2), a1);
        a0 = fmaf(whv.w, g3.x, a0); a1 = fmaf(whv.w, g3.y, a1);
        a0 = fmaf(atv.w, bl(v3), a0); a1 = fmaf(atv.w, bh(v3), a1);
        cx0[t] = a0; cx1[t] = a1;
      }
    }
    #pragma unroll
    for (int m8 = 0; m8 < 8; ++m8) {             // owA issue (v2a now dead)
      owA[2 * m8]     = W4o[c0 * 16 + m8];
      owA[2 * m8 + 1] = W4o[(c0 + 1) * 16 + m8];
    }
    #pragma unroll
    for (int n4 = 8; n4 < 16; ++n4) {            // rows 32..63 from v2b
      float2 g0 = v2b[4 * (n4 - 8) + 0];
      float2 g1 = v2b[4 * (n4 - 8) + 1];
      float2 g2 = v2b[4 * (n4 - 8) + 2];
      float2 g3 = v2b[4 * (n4 - 8) + 3];
      u32 v0 = vb[4 * n4 + 0];
      u32 v1 = vb[4 * n4 + 1];
      u32 v2 = vb[4 * n4 + 2];
      u32 v3 = vb[4 * n4 + 3];
      #pragma unroll
      for (int t = 0; t < 4; ++t) {
        float4 whv = *(const float4*)&qwhS[w][t][hd][4 * n4];
        float4 atv = *(const float4*)&atS[w][t][hd][4 * n4];
        float a0 = cx0[t], a1 = cx1[t];
        a0 = fmaf(whv.x, g0.x, a0); a1 = fmaf(whv.x, g0.y, a1);
        a0 = fmaf(atv.x, bl(v0), a0); a1 = fmaf(atv.x, bh(v0), a1);
        a0 = fmaf(whv.y, g1.x, a0); a1 = fmaf(whv.y, g1.y, a1);
        a0 = fmaf(atv.y, bl(v1), a0); a1 = fmaf(atv.y, bh(v1), a1);
        a0 = fmaf(whv.z, g2.x, a0); a1 = fmaf(whv.z, g2.y, a1);
        a0 = fmaf(atv.z, bl(v2), a0); a1 = fmaf(atv.z, bh(v2), a1);
        a0 = fmaf(whv.w, g3.x, a0); a1 = fmaf(whv.w, g3.y, a1);
        a0 = fmaf(atv.w, bl(v3), a0); a1 = fmaf(atv.w, bh(v3), a1);
        cx0[t] = a0; cx1[t] = a1;
      }
    }
    wsync();
    #pragma unroll
    for (int t = 0; t < 4; ++t)
      qSu[w][t][l] = pk(cx0[t], cx1[t]);             // ctx over q (packed)
  }
  wsync();

  // S8: attn_out = out_w @ ctx + out_b  (owA staged; owB + PWB-Q0 here)
  uint4 pf0[8], pg0[8];          // PWB quarter Q0 (m8 0..3), consumed in S9
  {
    float2 b = ((const float2*)ob)[l];
    float a0[4], a1[4];
    #pragma unroll
    for (int t = 0; t < 4; ++t) { a0[t] = b.x; a1[t] = b.y; }
    uint4 owB[16];
    #pragma unroll
    for (int m8 = 8; m8 < 16; ++m8) {
      owB[2 * (m8 - 8)]     = W4o[c0 * 16 + m8];
      owB[2 * (m8 - 8) + 1] = W4o[(c0 + 1) * 16 + m8];
    }
    #pragma unroll
    for (int m8 = 0; m8 < 8; ++m8) {
      #pragma unroll
      for (int t = 0; t < 4; ++t) {
        uint4 cp = *(const uint4*)&qSu[w][t][4 * m8];
        a0[t] = dot8b(owA[2 * m8],     cp, a0[t]);
        a1[t] = dot8b(owA[2 * m8 + 1], cp, a1[t]);
      }
    }
    #pragma unroll
    for (int k = 0; k < 4; ++k) {
      pf0[2 * k]     = W4p[c0 * 32 + k];
      pf0[2 * k + 1] = W4p[(c0 + 1) * 32 + k];
      pg0[2 * k]     = W4p[c0 * 32 + 16 + k];
      pg0[2 * k + 1] = W4p[(c0 + 1) * 32 + 16 + k];
    }
    #pragma unroll
    for (int m8 = 8; m8 < 16; ++m8) {
      #pragma unroll
      for (int t = 0; t < 4; ++t) {
        uint4 cp = *(const uint4*)&qSu[w][t][4 * m8];
        a0[t] = dot8b(owB[2 * (m8 - 8)],     cp, a0[t]);
        a1[t] = dot8b(owB[2 * (m8 - 8) + 1], cp, a1[t]);
      }
    }
    wsync();   // qwhS (wh) reads in S7 complete before overwrite
    #pragma unroll
    for (int t = 0; t < 4; ++t)
      ((u32*)&qwhS[w][t][0][0])[l] = pk(a0[t], a1[t]);
  }
  wsync();

  // S9: out = proj_w @ [feats; attn_out] + proj_b  (fp32 out)
  // Quartered: consume Qk while issuing Q(k+1). Per-m8 order ua,ub,uc,ud
  // with t inner — EXACTLY R11's sequence -> bit-identical accumulation.
  {
    float2 b = ((const float2*)pb)[l];
    float a0[4], a1[4];
    #pragma unroll
    for (int t = 0; t < 4; ++t) { a0[t] = b.x; a1[t] = b.y; }

    uint4 pf1[8], pg1[8];        // Q1 (m8 4..7)
    #pragma unroll
    for (int k = 0; k < 4; ++k) {
      pf1[2 * k]     = W4p[c0 * 32 + 4 + k];
      pf1[2 * k + 1] = W4p[(c0 + 1) * 32 + 4 + k];
      pg1[2 * k]     = W4p[c0 * 32 + 16 + 4 + k];
      pg1[2 * k + 1] = W4p[(c0 + 1) * 32 + 16 + 4 + k];
    }
    #pragma unroll
    for (int m8 = 0; m8 < 4; ++m8) {       // consume Q0
      #pragma unroll
      for (int t = 0; t < 4; ++t) {
        uint4 fp = *(const uint4*)&fqSu[w][t][4 * m8];
        uint4 gp = *(const uint4*)((const u32*)&qwhS[w][t][0][0] + 4 * m8);
        a0[t] = dot8b(pf0[2 * m8],     fp, a0[t]);
        a1[t] = dot8b(pf0[2 * m8 + 1], fp, a1[t]);
        a0[t] = dot8b(pg0[2 * m8],     gp, a0[t]);
        a1[t] = dot8b(pg0[2 * m8 + 1], gp, a1[t]);
      }
    }
    uint4 pf2[8], pg2[8];        // Q2 (m8 8..11)
    #pragma unroll
    for (int k = 0; k < 4; ++k) {
      pf2[2 * k]     = W4p[c0 * 32 + 8 + k];
      pf2[2 * k + 1] = W4p[(c0 + 1) * 32 + 8 + k];
      pg2[2 * k]     = W4p[c0 * 32 + 16 + 8 + k];
      pg2[2 * k + 1] = W4p[(c0 + 1) * 32 + 16 + 8 + k];
    }
    #pragma unroll
    for (int m8 = 4; m8 < 8; ++m8) {       // consume Q1
      #pragma unroll
      for (int t = 0; t < 4; ++t) {
        uint4 fp = *(const uint4*)&fqSu[w][t][4 * m8];
        uint4 gp = *(const uint4*)((const u32*)&qwhS[w][t][0][0] + 4 * m8);
        a0[t] = dot8b(pf1[2 * (m8 - 4)],     fp, a0[t]);
        a1[t] = dot8b(pf1[2 * (m8 - 4) + 1], fp, a1[t]);
        a0[t] = dot8b(pg1[2 * (m8 - 4)],     gp, a0[t]);
        a1[t] = dot8b(pg1[2 * (m8 - 4) + 1], gp, a1[t]);
      }
    }
    uint4 pf3[8], pg3[8];        // Q3 (m8 12..15)
    #pragma unroll
    for (int k = 0; k < 4; ++k) {
      pf3[2 * k]     = W4p[c0 * 32 + 12 + k];
      pf3[2 * k + 1] = W4p[(c0 + 1) * 32 + 12 + k];
      pg3[2 * k]     = W4p[c0 * 32 + 16 + 12 + k];
      pg3[2 * k + 1] = W4p[(c0 + 1) * 32 + 16 + 12 + k];
    }
    #pragma unroll
    for (int m8 = 8; m8 < 12; ++m8) {      // consume Q2
      #pragma unroll
      for (int t = 0; t < 4; ++t) {
        uint4 fp = *(const uint4*)&fqSu[w][t][4 * m8];
        uint4 gp = *(const uint4*)((const u32*)&qwhS[w][t][0][0] + 4 * m8);
        a0[t] = dot8b(pf2[2 * (m8 - 8)],     fp, a0[t]);
        a1[t] = dot8b(pf2[2 * (m8 - 8) + 1], fp, a1[t]);
        a0[t] = dot8b(pg2[2 * (m8 - 8)],     gp, a0[t]);
        a1[t] = dot8b(pg2[2 * (m8 - 8) + 1], gp, a1[t]);
      }
    }
    #pragma unroll
    for (int m8 = 12; m8 < 16; ++m8) {     // consume Q3
      #pragma unroll
      for (int t = 0; t < 4; ++t) {
        uint4 fp = *(const uint4*)&fqSu[w][t][4 * m8];
        uint4 gp = *(const uint4*)((const u32*)&qwhS[w][t][0][0] + 4 * m8);
        a0[t] = dot8b(pf3[2 * (m8 - 12)],     fp, a0[t]);
        a1[t] = dot8b(pf3[2 * (m8 - 12) + 1], fp, a1[t]);
        a0[t] = dot8b(pg3[2 * (m8 - 12)],     gp, a0[t]);
        a1[t] = dot8b(pg3[2 * (m8 - 12) + 1], gp, a1[t]);
      }
    }
    #pragma unroll
    for (int t = 0; t < 4; ++t)
      ((float2*)outp)[ig[t] * 64 + l] = make_float2(a0[t], a1[t]);
  }
}

extern "C" void kernel_launch(void* const* d_in, const int* in_sizes, int n_in,
                              void* d_out, int out_size, void* d_ws, size_t ws_size,
                              hipStream_t stream) {
  (void)in_sizes; (void)n_in; (void)out_size; (void)ws_size;
  const float* nf  = (const float*)d_in[0];
  const float* pos = (const float*)d_in[1];
  const float* w1  = (const float*)d_in[2];
  const float* b1  = (const float*)d_in[3];
  const float* w2  = (const float*)d_in[4];
  const float* b2  = (const float*)d_in[5];
  const float* ipw = (const float*)d_in[6];
  const float* ipb = (const float*)d_in[7];
  const float* ow  = (const float*)d_in[8];
  const float* ob  = (const float*)d_in[9];
  const float* pw  = (const float*)d_in[10];
  const float* pb  = (const float*)d_in[11];

  char* ws = (char*)d_ws;
  u32*   W2KB = (u32*)(ws);
  float* W2VT = (float*)(ws + (32 << 10));
  u32* WQB  = (u32*)(ws + (64 << 10));
  u32* OWB  = (u32*)(ws + (96 << 10));
  u32* PWB  = (u32*)(ws + (128 << 10));
  u32* KBt  = (u32*)(ws + (192 << 10));
  u32* VB   = (u32*)(ws + (192 << 10) + (128 * 4096 * 4));

  ee_setup<<<dim3(552), dim3(256), 0, stream>>>(nf, b2, ipw, ipb, w2, ow, pw,
                                                W2KB, W2VT, WQB, OWB, PWB, KBt, VB);
  ee_main<<<dim3(512), dim3(256), 0, stream>>>(nf, pos, w1, b1, ipb, ob, pb,
                                               W2KB, W2VT, WQB, OWB, PWB,
                                               KBt, VB, (float*)d_out);
}

// Round 9
// 162.750 us; speedup vs baseline: 1.0610x; 1.0610x over previous
//
#include <hip/hip_runtime.h>
#include <hip/hip_bf16.h>

// EdgeEncoder — fp32 inputs, algebraically folded attention:
//   k[i,j] = kbase[j] + W2k @ hid[i,j],   W2k = Wk @ W2
//   score  = q.kbase[j] + qw[i,hd].hid[i,j]
//   ctx    = sum_j attn*vbase[j] + W2v @ (sum_j attn*hid[i,j])
//
// R16 = R14 revert (68.8us) + W2VT staged WITHIN register budget.
// R15 post-mortem: fp32 W2VT staging (128 VGPR/lane) + WQB staging
// blew the allocator (VGPR chose 128, WRITE_SIZE 4096->20480KB = scratch
// spill, 81us). Fix the FORMAT: fold W2v to bf16 pairs (W2VB), layout
// transposed to per-lane-contiguous [cw][e] (same trick as W2KB/g4) ->
// 64 VGPR, 16 uint4 loads, issued top-of-S6 under the S6 FMA chain.
// S7 consumes bl/bh(v2p) in R14's exact FMA order (only bf16 rounding of
// W2v changes numerics; all other operands already bf16). WQB staging NOT
// re-added (one variable per round). Est peak VGPR ~210 < 256.
// Sentinel: WRITE_SIZE must stay ~4096KB (no spill), else revert to R14.
//
// ws layout (bytes):
//   [0,32K)     W2KB u32  [e][cw]   W2k bf16-pairs (16K used)
//   [32K,64K)   W2VB u32  [cw][e]   W2v bf16-pairs TRANSPOSED (16K used)
//   [64K,96K)   WQB  u32  [c][mw]   Wq bf16-pairs
//   [96K,128K)  OWB  u32  [c][mw]   out_w
//   [128K,192K) PWB  u32  [c][mw]   proj_w
//   [192K,+2M)  KBt  u32  [s][cw][j]  kbase bf16-pairs, j fastest
//   [+2M,+4M)   VB   u32  [s][j][cw]  vbase, cw fastest

typedef unsigned int u32;
#define SCALE 0.17677669529663689f   // 1/sqrt(32)

__device__ __forceinline__ float bl(u32 u){ union{u32 x; float f;} c; c.x = u << 16; return c.f; }
__device__ __forceinline__ float bh(u32 u){ union{u32 x; float f;} c; c.x = u & 0xffff0000u; return c.f; }
__device__ __forceinline__ u32 pk(float a, float b){
  union{float f; u32 x;} ca, cb; ca.f = a; cb.f = b;
  u32 ua = (ca.x + 0x7fffu + ((ca.x >> 16) & 1u)) >> 16;   // RNE fp32->bf16
  u32 ub = (cb.x + 0x7fffu + ((cb.x >> 16) & 1u)) >> 16;
  return ua | (ub << 16);
}

#if __has_builtin(__builtin_amdgcn_fdot2_f32_bf16)
__device__ __forceinline__ float dot2b(u32 a, u32 b, float c){
  float d;
  asm("v_dot2_f32_bf16 %0, %1, %2, %3" : "=v"(d) : "v"(a), "v"(b), "v"(c));
  return d;
}
#else
__device__ __forceinline__ float dot2b(u32 a, u32 b, float c){
  c = fmaf(bl(a), bl(b), c);
  return fmaf(bh(a), bh(b), c);
}
#endif
__device__ __forceinline__ float dot8b(uint4 wv, uint4 fv, float acc){
  acc = dot2b(wv.x, fv.x, acc);
  acc = dot2b(wv.y, fv.y, acc);
  acc = dot2b(wv.z, fv.z, acc);
  acc = dot2b(wv.w, fv.w, acc);
  return acc;
}
__device__ __forceinline__ void wsync(){
  __builtin_amdgcn_s_waitcnt(0xC07F);   // lgkmcnt(0)
  __builtin_amdgcn_wave_barrier();
}

// ---------------- kernel 1: setup (W2v now bf16-packed, transposed) ---------
__global__ __launch_bounds__(256, 2) void ee_setup(
    const float* __restrict__ nf, const float* __restrict__ b2,
    const float* __restrict__ ipw, const float* __restrict__ ipb,
    const float* __restrict__ w2,
    const float* __restrict__ ow, const float* __restrict__ pw,
    u32* __restrict__ W2KB, u32* __restrict__ W2VB,
    u32* __restrict__ WQB, u32* __restrict__ OWB, u32* __restrict__ PWB,
    u32* __restrict__ KBt, u32* __restrict__ VB)
{
  const int tid = threadIdx.x, b = blockIdx.x;
  const int cg = tid >> 6, l = tid & 63;
  const float2* ipw2 = (const float2*)ipw;
  const float2* ow2  = (const float2*)ow;
  const float2* pw2  = (const float2*)pw;

  if (b >= 544) {              // ---- weight packing, fully coalesced ----
    for (int k = 0; k < 16; ++k) {
      int i = (b - 544) * 4096 + k * 256 + tid;    // 0..32767
      if (i < 8192)       { float2 f = ipw2[i];        WQB[i]        = pk(f.x, f.y); }
      else if (i < 16384) { float2 f = ow2[i - 8192];  OWB[i - 8192] = pk(f.x, f.y); }
      else                { float2 f = pw2[i - 16384]; PWB[i - 16384]= pk(f.x, f.y); }
    }
    return;
  }
  if (b >= 512) {              // ---- W2 folds: W2x[ch][e] = Wk/Wv @ W2 ----
    int t = (b - 512) * 4 + cg;
    int kv = t & 1, e = t >> 1;
    int c0 = 2 * l;
    const float4* rp = (const float4*)ipw + (size_t)(128 + kv * 128 + c0) * 32;
    const float* w2e = w2 + __builtin_amdgcn_readfirstlane(e);
    float a0 = 0.f, a1 = 0.f;
    #pragma unroll 8
    for (int c4 = 0; c4 < 32; ++c4) {
      float4 wa = rp[c4], wb = rp[32 + c4];
      float x0 = w2e[(4 * c4 + 0) * 64];
      float x1 = w2e[(4 * c4 + 1) * 64];
      float x2 = w2e[(4 * c4 + 2) * 64];
      float x3 = w2e[(4 * c4 + 3) * 64];
      a0 = fmaf(wa.x, x0, a0); a0 = fmaf(wa.y, x1, a0);
      a0 = fmaf(wa.z, x2, a0); a0 = fmaf(wa.w, x3, a0);
      a1 = fmaf(wb.x, x0, a1); a1 = fmaf(wb.y, x1, a1);
      a1 = fmaf(wb.z, x2, a1); a1 = fmaf(wb.w, x3, a1);
    }
    if (kv) W2VB[l * 64 + e] = pk(a0, a1);     // transposed [cw=l][e]
    else    W2KB[e * 64 + l] = pk(a0, a1);
    return;
  }

  const int s = b >> 2, kv = (b >> 1) & 1, hlf = b & 1;
  __shared__ __align__(16) u32 fbS[64][68];
  __shared__ u32 vtS[64][33];
  const float2* nf2 = (const float2*)nf;
  const float2* b22 = (const float2*)b2;

  for (int idx = tid; idx < 4096; idx += 256) {
    int j = idx >> 6, mw = idx & 63;
    float2 f = nf2[((s << 6) + j) * 64 + mw];
    float2 bb = b22[mw];
    fbS[j][mw] = pk(f.x + bb.x, f.y + bb.y);
  }
  __syncthreads();

  uint4 fr[16];
  {
    const uint4* frow = (const uint4*)&fbS[l][0];
    #pragma unroll
    for (int k = 0; k < 16; ++k) fr[k] = frow[k];
  }
  #pragma unroll 1
  for (int p = 0; p < 8; ++p) {
    int c0 = hlf * 64 + cg * 16 + 2 * p;
    int r0 = 128 + kv * 128 + c0;
    const float4* w0 = (const float4*)ipw +
                       (size_t)__builtin_amdgcn_readfirstlane(r0) * 32;
    const float4* w1r = w0 + 32;
    float a0 = ipb[r0], a1 = ipb[r0 + 1];
    #pragma unroll
    for (int k = 0; k < 16; ++k) {
      uint4 F = fr[k];
      float4 wa = w0[2 * k],  wb = w0[2 * k + 1];
      float4 xa = w1r[2 * k], xb = w1r[2 * k + 1];
      float e0 = bl(F.x), e1 = bh(F.x), e2 = bl(F.y), e3 = bh(F.y);
      float e4 = bl(F.z), e5 = bh(F.z), e6 = bl(F.w), e7 = bh(F.w);
      a0 = fmaf(e0, wa.x, a0); a0 = fmaf(e1, wa.y, a0);
      a0 = fmaf(e2, wa.z, a0); a0 = fmaf(e3, wa.w, a0);
      a0 = fmaf(e4, wb.x, a0); a0 = fmaf(e5, wb.y, a0);
      a0 = fmaf(e6, wb.z, a0); a0 = fmaf(e7, wb.w, a0);
      a1 = fmaf(e0, xa.x, a1); a1 = fmaf(e1, xa.y, a1);
      a1 = fmaf(e2, xa.z, a1); a1 = fmaf(e3, xa.w, a1);
      a1 = fmaf(e4, xb.x, a1); a1 = fmaf(e5, xb.y, a1);
      a1 = fmaf(e6, xb.z, a1); a1 = fmaf(e7, xb.w, a1);
    }
    u32 v = pk(a0, a1);
    int cw = hlf * 32 + cg * 8 + p;
    if (kv == 0) KBt[(((s << 6) + cw) << 6) + l] = v;
    else         vtS[l][cg * 8 + p] = v;
  }
  if (kv == 1) {
    __syncthreads();
    int r = tid >> 2, cb = (tid & 3) * 8;
    #pragma unroll
    for (int k = 0; k < 8; ++k)
      VB[(((s << 6) + r) << 6) + hlf * 32 + cb + k] = vtS[r][cb + k];
  }
}

// ---------------- kernel 2: Q=4, wave-synchronous, staged prefetch ----------
__global__ __launch_bounds__(256, 2) void ee_main(
    const float* __restrict__ nf, const float* __restrict__ pos,
    const float* __restrict__ w1, const float* __restrict__ b1,
    const float* __restrict__ ipb,
    const float* __restrict__ ob, const float* __restrict__ pb,
    const u32* __restrict__ W2KB, const u32* __restrict__ W2VB,
    const u32* __restrict__ WQB, const u32* __restrict__ OWB,
    const u32* __restrict__ PWB,
    const u32* __restrict__ KBt, const u32* __restrict__ VB,
    float* __restrict__ outp)
{
  __shared__ __align__(16) float pxS[64], pyS[64], w1xS[64], w1yS[64], b1S[64];
  __shared__ __align__(16) u32 fqSu[4][4][68];       // feats bf16 pairs
  __shared__ __align__(16) u32 qSu [4][4][68];       // q -> ctx, bf16 pairs
  __shared__ __align__(16) float qwhS[4][4][4][68];  // qw (S4/S5) | wh | ao
  __shared__ __align__(16) float atS[4][4][4][68];   // at [w][t][hd][j]

  const int tid = threadIdx.x;
  const int s = blockIdx.x >> 2, qt = blockIdx.x & 3;
  const int w = tid >> 6, l = tid & 63;
  const int c0 = 2 * l;

  if (tid < 64) {
    float2 p = ((const float2*)pos)[(s << 6) + tid];
    pxS[tid] = p.x; pyS[tid] = p.y;
    float2 wv = ((const float2*)w1)[tid];
    w1xS[tid] = wv.x; w1yS[tid] = wv.y;
    b1S[tid] = b1[tid];
  }
  __syncthreads();
  // ---- no block barriers past here ----

  int il[4], ig[4];
  #pragma unroll
  for (int t = 0; t < 4; ++t) { il[t] = qt * 16 + 4 * w + t; ig[t] = (s << 6) + il[t]; }

  const uint4* W4o = (const uint4*)OWB;
  const uint4* W4p = (const uint4*)PWB;

  // S1: feats for 4 queries -> LDS (packed bf16 pairs)
  #pragma unroll
  for (int t = 0; t < 4; ++t) {
    float2 f = ((const float2*)nf)[ig[t] * 64 + l];
    fqSu[w][t][l] = pk(f.x, f.y);
  }
  wsync();

  // S2: q = Wq @ feats + bq  (dot2 pairs; weights reused x4)
  // g4 prefetch issued first — consumed in S4, hidden under S2's dot chain.
  uint4 g4[16];
  {
    const uint4* G4k = (const uint4*)W2KB + l * 16;
    #pragma unroll
    for (int i = 0; i < 16; ++i) g4[i] = G4k[i];
  }
  {
    float2 bq = ((const float2*)ipb)[l];
    float a0[4], a1[4];
    #pragma unroll
    for (int t = 0; t < 4; ++t) { a0[t] = bq.x; a1[t] = bq.y; }
    const uint4* W4 = (const uint4*)WQB;
    #pragma unroll 4
    for (int m8 = 0; m8 < 16; ++m8) {
      uint4 ua = W4[c0 * 16 + m8];
      uint4 ub = W4[(c0 + 1) * 16 + m8];
      #pragma unroll
      for (int t = 0; t < 4; ++t) {
        uint4 fp = *(const uint4*)&fqSu[w][t][4 * m8];
        a0[t] = dot8b(ua, fp, a0[t]);
        a1[t] = dot8b(ub, fp, a1[t]);
      }
    }
    #pragma unroll
    for (int t = 0; t < 4; ++t) qSu[w][t][l] = pk(a0[t], a1[t]);
  }
  wsync();

  // S4: qw[t][hd][e=l] = q_hd . W2k[:,e]_hd  (g4 staged; kb issued here)
  u32 kb[64];
  {
    const u32* kbp = KBt + (s << 12);
    #pragma unroll
    for (int j = 0; j < 64; ++j) kb[j] = kbp[(j << 6) + l];
  }
  {
    #pragma unroll
    for (int hd = 0; hd < 4; ++hd) {
      float acc[4] = {0.f, 0.f, 0.f, 0.f};
      #pragma unroll
      for (int dq2 = 0; dq2 < 4; ++dq2) {
        uint4 g = g4[hd * 4 + dq2];
        #pragma unroll
        for (int t = 0; t < 4; ++t) {
          uint4 qp = *(const uint4*)&qSu[w][t][hd * 16 + 4 * dq2];
          acc[t] = dot2b(g.x, qp.x, acc[t]);
          acc[t] = dot2b(g.y, qp.y, acc[t]);
          acc[t] = dot2b(g.z, qp.z, acc[t]);
          acc[t] = dot2b(g.w, qp.w, acc[t]);
        }
      }
      #pragma unroll
      for (int t = 0; t < 4; ++t) qwhS[w][t][hd][l] = acc[t];
    }
  }
  wsync();

  // S5: scores + softmax (lane = j; kb in registers, R11 order)
  float at[4][4];        // [t][hd]
  float pix[4], piy[4];
  {
    float pjx = pxS[l], pjy = pyS[l];
    float rx[4], ry[4];
    #pragma unroll
    for (int t = 0; t < 4; ++t) {
      pix[t] = pxS[il[t]]; piy[t] = pyS[il[t]];      // broadcast reads
      rx[t] = pjx - pix[t]; ry[t] = pjy - piy[t];
    }
    float sc[4][4];
    #pragma unroll
    for (int t = 0; t < 4; ++t)
      #pragma unroll
      for (int hd = 0; hd < 4; ++hd) sc[t][hd] = 0.f;

    #pragma unroll
    for (int m2 = 0; m2 < 32; ++m2) {
      u32 u0 = kb[2 * m2], u1 = kb[2 * m2 + 1];
      const int hd = m2 >> 3;
      #pragma unroll
      for (int t = 0; t < 4; ++t) {
        uint2 qp = *(const uint2*)&qSu[w][t][2 * m2];
        sc[t][hd] = dot2b(u0, qp.x, sc[t][hd]);
        sc[t][hd] = dot2b(u1, qp.y, sc[t][hd]);
      }
    }
    #pragma unroll 2
    for (int eb = 0; eb < 8; ++eb) {
      float4 wx0 = *(const float4*)&w1xS[8 * eb];
      float4 wx1 = *(const float4*)&w1xS[8 * eb + 4];
      float4 wy0 = *(const float4*)&w1yS[8 * eb];
      float4 wy1 = *(const float4*)&w1yS[8 * eb + 4];
      float4 bb0 = *(const float4*)&b1S[8 * eb];
      float4 bb1 = *(const float4*)&b1S[8 * eb + 4];
      #pragma unroll
      for (int t = 0; t < 4; ++t) {
        float h0 = fmaxf(0.f, fmaf(rx[t], wx0.x, fmaf(ry[t], wy0.x, bb0.x)));
        float h1 = fmaxf(0.f, fmaf(rx[t], wx0.y, fmaf(ry[t], wy0.y, bb0.y)));
        float h2 = fmaxf(0.f, fmaf(rx[t], wx0.z, fmaf(ry[t], wy0.z, bb0.z)));
        float h3 = fmaxf(0.f, fmaf(rx[t], wx0.w, fmaf(ry[t], wy0.w, bb0.w)));
        float h4 = fmaxf(0.f, fmaf(rx[t], wx1.x, fmaf(ry[t], wy1.x, bb1.x)));
        float h5 = fmaxf(0.f, fmaf(rx[t], wx1.y, fmaf(ry[t], wy1.y, bb1.y)));
        float h6 = fmaxf(0.f, fmaf(rx[t], wx1.z, fmaf(ry[t], wy1.z, bb1.z)));
        float h7 = fmaxf(0.f, fmaf(rx[t], wx1.w, fmaf(ry[t], wy1.w, bb1.w)));
        #pragma unroll
        for (int hd = 0; hd < 4; ++hd) {
          float4 q0 = *(const float4*)&qwhS[w][t][hd][8 * eb];
          float4 q1 = *(const float4*)&qwhS[w][t][hd][8 * eb + 4];
          float a = sc[t][hd];
          a = fmaf(q0.x, h0, a); a = fmaf(q0.y, h1, a);
          a = fmaf(q0.z, h2, a); a = fmaf(q0.w, h3, a);
          a = fmaf(q1.x, h4, a); a = fmaf(q1.y, h5, a);
          a = fmaf(q1.z, h6, a); a = fmaf(q1.w, h7, a);
          sc[t][hd] = a;
        }
      }
    }
    #pragma unroll
    for (int t = 0; t < 4; ++t) {
      #pragma unroll
      for (int hd = 0; hd < 4; ++hd) {
        float v = sc[t][hd] * SCALE;
        float m = v;
        #pragma unroll
        for (int off = 32; off > 0; off >>= 1) m = fmaxf(m, __shfl_xor(m, off));
        float p = __expf(v - m);
        float su = p;
        #pragma unroll
        for (int off = 32; off > 0; off >>= 1) su += __shfl_xor(su, off);
#if __has_builtin(__builtin_amdgcn_rcpf)
        at[t][hd] = p * __builtin_amdgcn_rcpf(su);
#else
        at[t][hd] = p / su;
#endif
        atS[w][t][hd][l] = at[t][hd];
      }
    }
  }
  wsync();

  // S6: wh[t][hd][e=l] = sum_j at*hid  (vb + v2p issued here, both 64 VGPR)
  u32 vb[64];
  {
    const u32* vbp = VB + (s << 12);
    #pragma unroll
    for (int j = 0; j < 64; ++j) vb[j] = vbp[(j << 6) + l];
  }
  uint4 v2p[16];               // W2VB, per-lane contiguous, consumed in S7
  {
    const uint4* Vt = (const uint4*)W2VB + l * 16;
    #pragma unroll
    for (int i = 0; i < 16; ++i) v2p[i] = Vt[i];
  }
  {
    float wx = w1xS[l], wy = w1yS[l], bb = b1S[l];
    float wh[4][4];
    #pragma unroll
    for (int t = 0; t < 4; ++t)
      #pragma unroll
      for (int hd = 0; hd < 4; ++hd) wh[t][hd] = 0.f;
    #pragma unroll 4
    for (int j4 = 0; j4 < 16; ++j4) {
      float4 px = *(const float4*)&pxS[4 * j4];
      float4 py = *(const float4*)&pyS[4 * j4];
      #pragma unroll
      for (int t = 0; t < 4; ++t) {
        float4 a0v = *(const float4*)&atS[w][t][0][4 * j4];
        float4 a1v = *(const float4*)&atS[w][t][1][4 * j4];
        float4 a2v = *(const float4*)&atS[w][t][2][4 * j4];
        float4 a3v = *(const float4*)&atS[w][t][3][4 * j4];
        float h;
        h = fmaxf(0.f, fmaf(px.x - pix[t], wx, fmaf(py.x - piy[t], wy, bb)));
        wh[t][0] = fmaf(a0v.x, h, wh[t][0]); wh[t][1] = fmaf(a1v.x, h, wh[t][1]);
        wh[t][2] = fmaf(a2v.x, h, wh[t][2]); wh[t][3] = fmaf(a3v.x, h, wh[t][3]);
        h = fmaxf(0.f, fmaf(px.y - pix[t], wx, fmaf(py.y - piy[t], wy, bb)));
        wh[t][0] = fmaf(a0v.y, h, wh[t][0]); wh[t][1] = fmaf(a1v.y, h, wh[t][1]);
        wh[t][2] = fmaf(a2v.y, h, wh[t][2]); wh[t][3] = fmaf(a3v.y, h, wh[t][3]);
        h = fmaxf(0.f, fmaf(px.z - pix[t], wx, fmaf(py.z - piy[t], wy, bb)));
        wh[t][0] = fmaf(a0v.z, h, wh[t][0]); wh[t][1] = fmaf(a1v.z, h, wh[t][1]);
        wh[t][2] = fmaf(a2v.z, h, wh[t][2]); wh[t][3] = fmaf(a3v.z, h, wh[t][3]);
        h = fmaxf(0.f, fmaf(px.w - pix[t], wx, fmaf(py.w - piy[t], wy, bb)));
        wh[t][0] = fmaf(a0v.w, h, wh[t][0]); wh[t][1] = fmaf(a1v.w, h, wh[t][1]);
        wh[t][2] = fmaf(a2v.w, h, wh[t][2]); wh[t][3] = fmaf(a3v.w, h, wh[t][3]);
      }
    }
    #pragma unroll
    for (int t = 0; t < 4; ++t)
      #pragma unroll
      for (int hd = 0; hd < 4; ++hd) qwhS[w][t][hd][l] = wh[t][hd];
  }
  wsync();

  // S7: ctx (vb + v2p in registers; owA issued here; R14 FMA order, W2v
  // values now bf16 via bl/bh of v2p)
  uint4 owA[16];
  {
    #pragma unroll
    for (int m8 = 0; m8 < 8; ++m8) {
      owA[2 * m8]     = W4o[c0 * 16 + m8];
      owA[2 * m8 + 1] = W4o[(c0 + 1) * 16 + m8];
    }
  }
  {
    const int hd = l >> 4;
    float cx0[4] = {0,0,0,0}, cx1[4] = {0,0,0,0};
    #pragma unroll
    for (int n4 = 0; n4 < 16; ++n4) {
      uint4 gq = v2p[n4];      // rows 4n4..4n4+3 of W2v, lane's channel pair
      u32 v0 = vb[4 * n4 + 0];
      u32 v1 = vb[4 * n4 + 1];
      u32 v2 = vb[4 * n4 + 2];
      u32 v3 = vb[4 * n4 + 3];
      #pragma unroll
      for (int t = 0; t < 4; ++t) {
        float4 whv = *(const float4*)&qwhS[w][t][hd][4 * n4];
        float4 atv = *(const float4*)&atS[w][t][hd][4 * n4];
        float a0 = cx0[t], a1 = cx1[t];
        a0 = fmaf(whv.x, bl(gq.x), a0); a1 = fmaf(whv.x, bh(gq.x), a1);
        a0 = fmaf(atv.x, bl(v0), a0);   a1 = fmaf(atv.x, bh(v0), a1);
        a0 = fmaf(whv.y, bl(gq.y), a0); a1 = fmaf(whv.y, bh(gq.y), a1);
        a0 = fmaf(atv.y, bl(v1), a0);   a1 = fmaf(atv.y, bh(v1), a1);
        a0 = fmaf(whv.z, bl(gq.z), a0); a1 = fmaf(whv.z, bh(gq.z), a1);
        a0 = fmaf(atv.z, bl(v2), a0);   a1 = fmaf(atv.z, bh(v2), a1);
        a0 = fmaf(whv.w, bl(gq.w), a0); a1 = fmaf(whv.w, bh(gq.w), a1);
        a0 = fmaf(atv.w, bl(v3), a0);   a1 = fmaf(atv.w, bh(v3), a1);
        cx0[t] = a0; cx1[t] = a1;
      }
    }
    wsync();
    #pragma unroll
    for (int t = 0; t < 4; ++t)
      qSu[w][t][l] = pk(cx0[t], cx1[t]);             // ctx over q (packed)
  }
  wsync();

  // S8: attn_out = out_w @ ctx + out_b  (owA staged; owB + PWB-Q0 here)
  uint4 pf0[8], pg0[8];          // PWB quarter Q0 (m8 0..3), consumed in S9
  {
    float2 b = ((const float2*)ob)[l];
    float a0[4], a1[4];
    #pragma unroll
    for (int t = 0; t < 4; ++t) { a0[t] = b.x; a1[t] = b.y; }
    uint4 owB[16];
    #pragma unroll
    for (int m8 = 8; m8 < 16; ++m8) {
      owB[2 * (m8 - 8)]     = W4o[c0 * 16 + m8];
      owB[2 * (m8 - 8) + 1] = W4o[(c0 + 1) * 16 + m8];
    }
    #pragma unroll
    for (int m8 = 0; m8 < 8; ++m8) {
      #pragma unroll
      for (int t = 0; t < 4; ++t) {
        uint4 cp = *(const uint4*)&qSu[w][t][4 * m8];
        a0[t] = dot8b(owA[2 * m8],     cp, a0[t]);
        a1[t] = dot8b(owA[2 * m8 + 1], cp, a1[t]);
      }
    }
    #pragma unroll
    for (int k = 0; k < 4; ++k) {
      pf0[2 * k]     = W4p[c0 * 32 + k];
      pf0[2 * k + 1] = W4p[(c0 + 1) * 32 + k];
      pg0[2 * k]     = W4p[c0 * 32 + 16 + k];
      pg0[2 * k + 1] = W4p[(c0 + 1) * 32 + 16 + k];
    }
    #pragma unroll
    for (int m8 = 8; m8 < 16; ++m8) {
      #pragma unroll
      for (int t = 0; t < 4; ++t) {
        uint4 cp = *(const uint4*)&qSu[w][t][4 * m8];
        a0[t] = dot8b(owB[2 * (m8 - 8)],     cp, a0[t]);
        a1[t] = dot8b(owB[2 * (m8 - 8) + 1], cp, a1[t]);
      }
    }
    wsync();   // qwhS (wh) reads in S7 complete before overwrite
    #pragma unroll
    for (int t = 0; t < 4; ++t)
      ((u32*)&qwhS[w][t][0][0])[l] = pk(a0[t], a1[t]);
  }
  wsync();

  // S9: out = proj_w @ [feats; attn_out] + proj_b  (fp32 out)
  // Quartered: consume Qk while issuing Q(k+1). Per-m8 order ua,ub,uc,ud
  // with t inner — EXACTLY R11's sequence -> bit-identical accumulation.
  {
    float2 b = ((const float2*)pb)[l];
    float a0[4], a1[4];
    #pragma unroll
    for (int t = 0; t < 4; ++t) { a0[t] = b.x; a1[t] = b.y; }

    uint4 pf1[8], pg1[8];        // Q1 (m8 4..7)
    #pragma unroll
    for (int k = 0; k < 4; ++k) {
      pf1[2 * k]     = W4p[c0 * 32 + 4 + k];
      pf1[2 * k + 1] = W4p[(c0 + 1) * 32 + 4 + k];
      pg1[2 * k]     = W4p[c0 * 32 + 16 + 4 + k];
      pg1[2 * k + 1] = W4p[(c0 + 1) * 32 + 16 + 4 + k];
    }
    #pragma unroll
    for (int m8 = 0; m8 < 4; ++m8) {       // consume Q0
      #pragma unroll
      for (int t = 0; t < 4; ++t) {
        uint4 fp = *(const uint4*)&fqSu[w][t][4 * m8];
        uint4 gp = *(const uint4*)((const u32*)&qwhS[w][t][0][0] + 4 * m8);
        a0[t] = dot8b(pf0[2 * m8],     fp, a0[t]);
        a1[t] = dot8b(pf0[2 * m8 + 1], fp, a1[t]);
        a0[t] = dot8b(pg0[2 * m8],     gp, a0[t]);
        a1[t] = dot8b(pg0[2 * m8 + 1], gp, a1[t]);
      }
    }
    uint4 pf2[8], pg2[8];        // Q2 (m8 8..11)
    #pragma unroll
    for (int k = 0; k < 4; ++k) {
      pf2[2 * k]     = W4p[c0 * 32 + 8 + k];
      pf2[2 * k + 1] = W4p[(c0 + 1) * 32 + 8 + k];
      pg2[2 * k]     = W4p[c0 * 32 + 16 + 8 + k];
      pg2[2 * k + 1] = W4p[(c0 + 1) * 32 + 16 + 8 + k];
    }
    #pragma unroll
    for (int m8 = 4; m8 < 8; ++m8) {       // consume Q1
      #pragma unroll
      for (int t = 0; t < 4; ++t) {
        uint4 fp = *(const uint4*)&fqSu[w][t][4 * m8];
        uint4 gp = *(const uint4*)((const u32*)&qwhS[w][t][0][0] + 4 * m8);
        a0[t] = dot8b(pf1[2 * (m8 - 4)],     fp, a0[t]);
        a1[t] = dot8b(pf1[2 * (m8 - 4) + 1], fp, a1[t]);
        a0[t] = dot8b(pg1[2 * (m8 - 4)],     gp, a0[t]);
        a1[t] = dot8b(pg1[2 * (m8 - 4) + 1], gp, a1[t]);
      }
    }
    uint4 pf3[8], pg3[8];        // Q3 (m8 12..15)
    #pragma unroll
    for (int k = 0; k < 4; ++k) {
      pf3[2 * k]     = W4p[c0 * 32 + 12 + k];
      pf3[2 * k + 1] = W4p[(c0 + 1) * 32 + 12 + k];
      pg3[2 * k]     = W4p[c0 * 32 + 16 + 12 + k];
      pg3[2 * k + 1] = W4p[(c0 + 1) * 32 + 16 + 12 + k];
    }
    #pragma unroll
    for (int m8 = 8; m8 < 12; ++m8) {      // consume Q2
      #pragma unroll
      for (int t = 0; t < 4; ++t) {
        uint4 fp = *(const uint4*)&fqSu[w][t][4 * m8];
        uint4 gp = *(const uint4*)((const u32*)&qwhS[w][t][0][0] + 4 * m8);
        a0[t] = dot8b(pf2[2 * (m8 - 8)],     fp, a0[t]);
        a1[t] = dot8b(pf2[2 * (m8 - 8) + 1], fp, a1[t]);
        a0[t] = dot8b(pg2[2 * (m8 - 8)],     gp, a0[t]);
        a1[t] = dot8b(pg2[2 * (m8 - 8) + 1], gp, a1[t]);
      }
    }
    #pragma unroll
    for (int m8 = 12; m8 < 16; ++m8) {     // consume Q3
      #pragma unroll
      for (int t = 0; t < 4; ++t) {
        uint4 fp = *(const uint4*)&fqSu[w][t][4 * m8];
        uint4 gp = *(const uint4*)((const u32*)&qwhS[w][t][0][0] + 4 * m8);
        a0[t] = dot8b(pf3[2 * (m8 - 12)],     fp, a0[t]);
        a1[t] = dot8b(pf3[2 * (m8 - 12) + 1], fp, a1[t]);
        a0[t] = dot8b(pg3[2 * (m8 - 12)],     gp, a0[t]);
        a1[t] = dot8b(pg3[2 * (m8 - 12) + 1], gp, a1[t]);
      }
    }
    #pragma unroll
    for (int t = 0; t < 4; ++t)
      ((float2*)outp)[ig[t] * 64 + l] = make_float2(a0[t], a1[t]);
  }
}

extern "C" void kernel_launch(void* const* d_in, const int* in_sizes, int n_in,
                              void* d_out, int out_size, void* d_ws, size_t ws_size,
                              hipStream_t stream) {
  (void)in_sizes; (void)n_in; (void)out_size; (void)ws_size;
  const float* nf  = (const float*)d_in[0];
  const float* pos = (const float*)d_in[1];
  const float* w1  = (const float*)d_in[2];
  const float* b1  = (const float*)d_in[3];
  const float* w2  = (const float*)d_in[4];
  const float* b2  = (const float*)d_in[5];
  const float* ipw = (const float*)d_in[6];
  const float* ipb = (const float*)d_in[7];
  const float* ow  = (const float*)d_in[8];
  const float* ob  = (const float*)d_in[9];
  const float* pw  = (const float*)d_in[10];
  const float* pb  = (const float*)d_in[11];

  char* ws = (char*)d_ws;
  u32* W2KB = (u32*)(ws);
  u32* W2VB = (u32*)(ws + (32 << 10));
  u32* WQB  = (u32*)(ws + (64 << 10));
  u32* OWB  = (u32*)(ws + (96 << 10));
  u32* PWB  = (u32*)(ws + (128 << 10));
  u32* KBt  = (u32*)(ws + (192 << 10));
  u32* VB   = (u32*)(ws + (192 << 10) + (128 * 4096 * 4));

  ee_setup<<<dim3(552), dim3(256), 0, stream>>>(nf, b2, ipw, ipb, w2, ow, pw,
                                                W2KB, W2VB, WQB, OWB, PWB, KBt, VB);
  ee_main<<<dim3(512), dim3(256), 0, stream>>>(nf, pos, w1, b1, ipb, ob, pb,
                                               W2KB, W2VB, WQB, OWB, PWB,
                                               KBt, VB, (float*)d_out);
}

// Round 11
// 161.703 us; speedup vs baseline: 1.0678x; 1.0065x over previous
//
#include <hip/hip_runtime.h>
#include <hip/hip_bf16.h>

// EdgeEncoder — fp32 inputs, algebraically folded attention:
//   k[i,j] = kbase[j] + W2k @ hid[i,j],   W2k = Wk @ W2
//   score  = q.kbase[j] + qw[i,hd].hid[i,j]
//   ctx    = sum_j attn*vbase[j] + W2v @ (sum_j attn*hid[i,j])
//
// R18 = R16 (68.0us, passed) + amdgpu_waves_per_eu(2,2) pin ONLY.
// R17 post-mortem: R16+{pin, WQB staging} failed at absmax 0.195 despite
// bit-identical arithmetic order => miscompile/scheduling hazard, not an
// arithmetic bug. Failure set {R12,R17} vs pass set {R15,R16} implicates
// stacking >4 staged register arrays; can't bisect pin vs WQB-staging by
// reasoning. R18 tests the CHEAP half: pin only, R16 code otherwise
// byte-identical. Purpose of pin: R16's allocator self-capped at VGPR=128
// and spilled ~1MB (WRITE 4096->5120KB); grid caps occupancy at 2
// blocks/CU anyway, so the full 256-VGPR budget is free.
//  - pass => pin innocent; R17's bug was WQB-staging interaction. Keep.
//  - fail => pin miscompiles; terminal kernel is R16.
// Sentinels: absmax 0.015625 exactly; WRITE_SIZE ~4096KB; VGPR >128.
//
// ws layout (bytes):
//   [0,32K)     W2KB u32  [e][cw]   W2k bf16-pairs (16K used)
//   [32K,64K)   W2VB u32  [cw][e]   W2v bf16-pairs TRANSPOSED (16K used)
//   [64K,96K)   WQB  u32  [c][mw]   Wq bf16-pairs
//   [96K,128K)  OWB  u32  [c][mw]   out_w
//   [128K,192K) PWB  u32  [c][mw]   proj_w
//   [192K,+2M)  KBt  u32  [s][cw][j]  kbase bf16-pairs, j fastest
//   [+2M,+4M)   VB   u32  [s][j][cw]  vbase, cw fastest

typedef unsigned int u32;
#define SCALE 0.17677669529663689f   // 1/sqrt(32)

__device__ __forceinline__ float bl(u32 u){ union{u32 x; float f;} c; c.x = u << 16; return c.f; }
__device__ __forceinline__ float bh(u32 u){ union{u32 x; float f;} c; c.x = u & 0xffff0000u; return c.f; }
__device__ __forceinline__ u32 pk(float a, float b){
  union{float f; u32 x;} ca, cb; ca.f = a; cb.f = b;
  u32 ua = (ca.x + 0x7fffu + ((ca.x >> 16) & 1u)) >> 16;   // RNE fp32->bf16
  u32 ub = (cb.x + 0x7fffu + ((cb.x >> 16) & 1u)) >> 16;
  return ua | (ub << 16);
}

#if __has_builtin(__builtin_amdgcn_fdot2_f32_bf16)
__device__ __forceinline__ float dot2b(u32 a, u32 b, float c){
  float d;
  asm("v_dot2_f32_bf16 %0, %1, %2, %3" : "=v"(d) : "v"(a), "v"(b), "v"(c));
  return d;
}
#else
__device__ __forceinline__ float dot2b(u32 a, u32 b, float c){
  c = fmaf(bl(a), bl(b), c);
  return fmaf(bh(a), bh(b), c);
}
#endif
__device__ __forceinline__ float dot8b(uint4 wv, uint4 fv, float acc){
  acc = dot2b(wv.x, fv.x, acc);
  acc = dot2b(wv.y, fv.y, acc);
  acc = dot2b(wv.z, fv.z, acc);
  acc = dot2b(wv.w, fv.w, acc);
  return acc;
}
__device__ __forceinline__ void wsync(){
  __builtin_amdgcn_s_waitcnt(0xC07F);   // lgkmcnt(0)
  __builtin_amdgcn_wave_barrier();
}

// ---------------- kernel 1: setup (unchanged from R16) ----------------------
__global__ __launch_bounds__(256, 2) void ee_setup(
    const float* __restrict__ nf, const float* __restrict__ b2,
    const float* __restrict__ ipw, const float* __restrict__ ipb,
    const float* __restrict__ w2,
    const float* __restrict__ ow, const float* __restrict__ pw,
    u32* __restrict__ W2KB, u32* __restrict__ W2VB,
    u32* __restrict__ WQB, u32* __restrict__ OWB, u32* __restrict__ PWB,
    u32* __restrict__ KBt, u32* __restrict__ VB)
{
  const int tid = threadIdx.x, b = blockIdx.x;
  const int cg = tid >> 6, l = tid & 63;
  const float2* ipw2 = (const float2*)ipw;
  const float2* ow2  = (const float2*)ow;
  const float2* pw2  = (const float2*)pw;

  if (b >= 544) {              // ---- weight packing, fully coalesced ----
    for (int k = 0; k < 16; ++k) {
      int i = (b - 544) * 4096 + k * 256 + tid;    // 0..32767
      if (i < 8192)       { float2 f = ipw2[i];        WQB[i]        = pk(f.x, f.y); }
      else if (i < 16384) { float2 f = ow2[i - 8192];  OWB[i - 8192] = pk(f.x, f.y); }
      else                { float2 f = pw2[i - 16384]; PWB[i - 16384]= pk(f.x, f.y); }
    }
    return;
  }
  if (b >= 512) {              // ---- W2 folds: W2x[ch][e] = Wk/Wv @ W2 ----
    int t = (b - 512) * 4 + cg;
    int kv = t & 1, e = t >> 1;
    int c0 = 2 * l;
    const float4* rp = (const float4*)ipw + (size_t)(128 + kv * 128 + c0) * 32;
    const float* w2e = w2 + __builtin_amdgcn_readfirstlane(e);
    float a0 = 0.f, a1 = 0.f;
    #pragma unroll 8
    for (int c4 = 0; c4 < 32; ++c4) {
      float4 wa = rp[c4], wb = rp[32 + c4];
      float x0 = w2e[(4 * c4 + 0) * 64];
      float x1 = w2e[(4 * c4 + 1) * 64];
      float x2 = w2e[(4 * c4 + 2) * 64];
      float x3 = w2e[(4 * c4 + 3) * 64];
      a0 = fmaf(wa.x, x0, a0); a0 = fmaf(wa.y, x1, a0);
      a0 = fmaf(wa.z, x2, a0); a0 = fmaf(wa.w, x3, a0);
      a1 = fmaf(wb.x, x0, a1); a1 = fmaf(wb.y, x1, a1);
      a1 = fmaf(wb.z, x2, a1); a1 = fmaf(wb.w, x3, a1);
    }
    if (kv) W2VB[l * 64 + e] = pk(a0, a1);     // transposed [cw=l][e]
    else    W2KB[e * 64 + l] = pk(a0, a1);
    return;
  }

  const int s = b >> 2, kv = (b >> 1) & 1, hlf = b & 1;
  __shared__ __align__(16) u32 fbS[64][68];
  __shared__ u32 vtS[64][33];
  const float2* nf2 = (const float2*)nf;
  const float2* b22 = (const float2*)b2;

  for (int idx = tid; idx < 4096; idx += 256) {
    int j = idx >> 6, mw = idx & 63;
    float2 f = nf2[((s << 6) + j) * 64 + mw];
    float2 bb = b22[mw];
    fbS[j][mw] = pk(f.x + bb.x, f.y + bb.y);
  }
  __syncthreads();

  uint4 fr[16];
  {
    const uint4* frow = (const uint4*)&fbS[l][0];
    #pragma unroll
    for (int k = 0; k < 16; ++k) fr[k] = frow[k];
  }
  #pragma unroll 1
  for (int p = 0; p < 8; ++p) {
    int c0 = hlf * 64 + cg * 16 + 2 * p;
    int r0 = 128 + kv * 128 + c0;
    const float4* w0 = (const float4*)ipw +
                       (size_t)__builtin_amdgcn_readfirstlane(r0) * 32;
    const float4* w1r = w0 + 32;
    float a0 = ipb[r0], a1 = ipb[r0 + 1];
    #pragma unroll
    for (int k = 0; k < 16; ++k) {
      uint4 F = fr[k];
      float4 wa = w0[2 * k],  wb = w0[2 * k + 1];
      float4 xa = w1r[2 * k], xb = w1r[2 * k + 1];
      float e0 = bl(F.x), e1 = bh(F.x), e2 = bl(F.y), e3 = bh(F.y);
      float e4 = bl(F.z), e5 = bh(F.z), e6 = bl(F.w), e7 = bh(F.w);
      a0 = fmaf(e0, wa.x, a0); a0 = fmaf(e1, wa.y, a0);
      a0 = fmaf(e2, wa.z, a0); a0 = fmaf(e3, wa.w, a0);
      a0 = fmaf(e4, wb.x, a0); a0 = fmaf(e5, wb.y, a0);
      a0 = fmaf(e6, wb.z, a0); a0 = fmaf(e7, wb.w, a0);
      a1 = fmaf(e0, xa.x, a1); a1 = fmaf(e1, xa.y, a1);
      a1 = fmaf(e2, xa.z, a1); a1 = fmaf(e3, xa.w, a1);
      a1 = fmaf(e4, xb.x, a1); a1 = fmaf(e5, xb.y, a1);
      a1 = fmaf(e6, xb.z, a1); a1 = fmaf(e7, xb.w, a1);
    }
    u32 v = pk(a0, a1);
    int cw = hlf * 32 + cg * 8 + p;
    if (kv == 0) KBt[(((s << 6) + cw) << 6) + l] = v;
    else         vtS[l][cg * 8 + p] = v;
  }
  if (kv == 1) {
    __syncthreads();
    int r = tid >> 2, cb = (tid & 3) * 8;
    #pragma unroll
    for (int k = 0; k < 8; ++k)
      VB[(((s << 6) + r) << 6) + hlf * 32 + cb + k] = vtS[r][cb + k];
  }
}

// ---------------- kernel 2: Q=4, wave-synchronous, staged prefetch ----------
// R16 code byte-identical; ONLY change is the occupancy pin. Grid caps at
// 2 blocks/CU anyway; pin hands the allocator the full 256-VGPR budget so
// the R16 staging arrays stay in registers instead of spilling (~1MB).
__global__ __launch_bounds__(256)
__attribute__((amdgpu_waves_per_eu(2, 2))) void ee_main(
    const float* __restrict__ nf, const float* __restrict__ pos,
    const float* __restrict__ w1, const float* __restrict__ b1,
    const float* __restrict__ ipb,
    const float* __restrict__ ob, const float* __restrict__ pb,
    const u32* __restrict__ W2KB, const u32* __restrict__ W2VB,
    const u32* __restrict__ WQB, const u32* __restrict__ OWB,
    const u32* __restrict__ PWB,
    const u32* __restrict__ KBt, const u32* __restrict__ VB,
    float* __restrict__ outp)
{
  __shared__ __align__(16) float pxS[64], pyS[64], w1xS[64], w1yS[64], b1S[64];
  __shared__ __align__(16) u32 fqSu[4][4][68];       // feats bf16 pairs
  __shared__ __align__(16) u32 qSu [4][4][68];       // q -> ctx, bf16 pairs
  __shared__ __align__(16) float qwhS[4][4][4][68];  // qw (S4/S5) | wh | ao
  __shared__ __align__(16) float atS[4][4][4][68];   // at [w][t][hd][j]

  const int tid = threadIdx.x;
  const int s = blockIdx.x >> 2, qt = blockIdx.x & 3;
  const int w = tid >> 6, l = tid & 63;
  const int c0 = 2 * l;

  if (tid < 64) {
    float2 p = ((const float2*)pos)[(s << 6) + tid];
    pxS[tid] = p.x; pyS[tid] = p.y;
    float2 wv = ((const float2*)w1)[tid];
    w1xS[tid] = wv.x; w1yS[tid] = wv.y;
    b1S[tid] = b1[tid];
  }
  __syncthreads();
  // ---- no block barriers past here ----

  int il[4], ig[4];
  #pragma unroll
  for (int t = 0; t < 4; ++t) { il[t] = qt * 16 + 4 * w + t; ig[t] = (s << 6) + il[t]; }

  const uint4* W4o = (const uint4*)OWB;
  const uint4* W4p = (const uint4*)PWB;

  // S1: feats for 4 queries -> LDS (packed bf16 pairs)
  #pragma unroll
  for (int t = 0; t < 4; ++t) {
    float2 f = ((const float2*)nf)[ig[t] * 64 + l];
    fqSu[w][t][l] = pk(f.x, f.y);
  }
  wsync();

  // S2: q = Wq @ feats + bq  (dot2 pairs; weights reused x4)
  // g4 prefetch issued first — consumed in S4, hidden under S2's dot chain.
  uint4 g4[16];
  {
    const uint4* G4k = (const uint4*)W2KB + l * 16;
    #pragma unroll
    for (int i = 0; i < 16; ++i) g4[i] = G4k[i];
  }
  {
    float2 bq = ((const float2*)ipb)[l];
    float a0[4], a1[4];
    #pragma unroll
    for (int t = 0; t < 4; ++t) { a0[t] = bq.x; a1[t] = bq.y; }
    const uint4* W4 = (const uint4*)WQB;
    #pragma unroll 4
    for (int m8 = 0; m8 < 16; ++m8) {
      uint4 ua = W4[c0 * 16 + m8];
      uint4 ub = W4[(c0 + 1) * 16 + m8];
      #pragma unroll
      for (int t = 0; t < 4; ++t) {
        uint4 fp = *(const uint4*)&fqSu[w][t][4 * m8];
        a0[t] = dot8b(ua, fp, a0[t]);
        a1[t] = dot8b(ub, fp, a1[t]);
      }
    }
    #pragma unroll
    for (int t = 0; t < 4; ++t) qSu[w][t][l] = pk(a0[t], a1[t]);
  }
  wsync();

  // S4: qw[t][hd][e=l] = q_hd . W2k[:,e]_hd  (g4 staged; kb issued here)
  u32 kb[64];
  {
    const u32* kbp = KBt + (s << 12);
    #pragma unroll
    for (int j = 0; j < 64; ++j) kb[j] = kbp[(j << 6) + l];
  }
  {
    #pragma unroll
    for (int hd = 0; hd < 4; ++hd) {
      float acc[4] = {0.f, 0.f, 0.f, 0.f};
      #pragma unroll
      for (int dq2 = 0; dq2 < 4; ++dq2) {
        uint4 g = g4[hd * 4 + dq2];
        #pragma unroll
        for (int t = 0; t < 4; ++t) {
          uint4 qp = *(const uint4*)&qSu[w][t][hd * 16 + 4 * dq2];
          acc[t] = dot2b(g.x, qp.x, acc[t]);
          acc[t] = dot2b(g.y, qp.y, acc[t]);
          acc[t] = dot2b(g.z, qp.z, acc[t]);
          acc[t] = dot2b(g.w, qp.w, acc[t]);
        }
      }
      #pragma unroll
      for (int t = 0; t < 4; ++t) qwhS[w][t][hd][l] = acc[t];
    }
  }
  wsync();

  // S5: scores + softmax (lane = j; kb in registers, R11 order)
  float at[4][4];        // [t][hd]
  float pix[4], piy[4];
  {
    float pjx = pxS[l], pjy = pyS[l];
    float rx[4], ry[4];
    #pragma unroll
    for (int t = 0; t < 4; ++t) {
      pix[t] = pxS[il[t]]; piy[t] = pyS[il[t]];      // broadcast reads
      rx[t] = pjx - pix[t]; ry[t] = pjy - piy[t];
    }
    float sc[4][4];
    #pragma unroll
    for (int t = 0; t < 4; ++t)
      #pragma unroll
      for (int hd = 0; hd < 4; ++hd) sc[t][hd] = 0.f;

    #pragma unroll
    for (int m2 = 0; m2 < 32; ++m2) {
      u32 u0 = kb[2 * m2], u1 = kb[2 * m2 + 1];
      const int hd = m2 >> 3;
      #pragma unroll
      for (int t = 0; t < 4; ++t) {
        uint2 qp = *(const uint2*)&qSu[w][t][2 * m2];
        sc[t][hd] = dot2b(u0, qp.x, sc[t][hd]);
        sc[t][hd] = dot2b(u1, qp.y, sc[t][hd]);
      }
    }
    #pragma unroll 2
    for (int eb = 0; eb < 8; ++eb) {
      float4 wx0 = *(const float4*)&w1xS[8 * eb];
      float4 wx1 = *(const float4*)&w1xS[8 * eb + 4];
      float4 wy0 = *(const float4*)&w1yS[8 * eb];
      float4 wy1 = *(const float4*)&w1yS[8 * eb + 4];
      float4 bb0 = *(const float4*)&b1S[8 * eb];
      float4 bb1 = *(const float4*)&b1S[8 * eb + 4];
      #pragma unroll
      for (int t = 0; t < 4; ++t) {
        float h0 = fmaxf(0.f, fmaf(rx[t], wx0.x, fmaf(ry[t], wy0.x, bb0.x)));
        float h1 = fmaxf(0.f, fmaf(rx[t], wx0.y, fmaf(ry[t], wy0.y, bb0.y)));
        float h2 = fmaxf(0.f, fmaf(rx[t], wx0.z, fmaf(ry[t], wy0.z, bb0.z)));
        float h3 = fmaxf(0.f, fmaf(rx[t], wx0.w, fmaf(ry[t], wy0.w, bb0.w)));
        float h4 = fmaxf(0.f, fmaf(rx[t], wx1.x, fmaf(ry[t], wy1.x, bb1.x)));
        float h5 = fmaxf(0.f, fmaf(rx[t], wx1.y, fmaf(ry[t], wy1.y, bb1.y)));
        float h6 = fmaxf(0.f, fmaf(rx[t], wx1.z, fmaf(ry[t], wy1.z, bb1.z)));
        float h7 = fmaxf(0.f, fmaf(rx[t], wx1.w, fmaf(ry[t], wy1.w, bb1.w)));
        #pragma unroll
        for (int hd = 0; hd < 4; ++hd) {
          float4 q0 = *(const float4*)&qwhS[w][t][hd][8 * eb];
          float4 q1 = *(const float4*)&qwhS[w][t][hd][8 * eb + 4];
          float a = sc[t][hd];
          a = fmaf(q0.x, h0, a); a = fmaf(q0.y, h1, a);
          a = fmaf(q0.z, h2, a); a = fmaf(q0.w, h3, a);
          a = fmaf(q1.x, h4, a); a = fmaf(q1.y, h5, a);
          a = fmaf(q1.z, h6, a); a = fmaf(q1.w, h7, a);
          sc[t][hd] = a;
        }
      }
    }
    #pragma unroll
    for (int t = 0; t < 4; ++t) {
      #pragma unroll
      for (int hd = 0; hd < 4; ++hd) {
        float v = sc[t][hd] * SCALE;
        float m = v;
        #pragma unroll
        for (int off = 32; off > 0; off >>= 1) m = fmaxf(m, __shfl_xor(m, off));
        float p = __expf(v - m);
        float su = p;
        #pragma unroll
        for (int off = 32; off > 0; off >>= 1) su += __shfl_xor(su, off);
#if __has_builtin(__builtin_amdgcn_rcpf)
        at[t][hd] = p * __builtin_amdgcn_rcpf(su);
#else
        at[t][hd] = p / su;
#endif
        atS[w][t][hd][l] = at[t][hd];
      }
    }
  }
  wsync();

  // S6: wh[t][hd][e=l] = sum_j at*hid  (vb + v2p issued here, both 64 VGPR)
  u32 vb[64];
  {
    const u32* vbp = VB + (s << 12);
    #pragma unroll
    for (int j = 0; j < 64; ++j) vb[j] = vbp[(j << 6) + l];
  }
  uint4 v2p[16];               // W2VB, per-lane contiguous, consumed in S7
  {
    const uint4* Vt = (const uint4*)W2VB + l * 16;
    #pragma unroll
    for (int i = 0; i < 16; ++i) v2p[i] = Vt[i];
  }
  {
    float wx = w1xS[l], wy = w1yS[l], bb = b1S[l];
    float wh[4][4];
    #pragma unroll
    for (int t = 0; t < 4; ++t)
      #pragma unroll
      for (int hd = 0; hd < 4; ++hd) wh[t][hd] = 0.f;
    #pragma unroll 4
    for (int j4 = 0; j4 < 16; ++j4) {
      float4 px = *(const float4*)&pxS[4 * j4];
      float4 py = *(const float4*)&pyS[4 * j4];
      #pragma unroll
      for (int t = 0; t < 4; ++t) {
        float4 a0v = *(const float4*)&atS[w][t][0][4 * j4];
        float4 a1v = *(const float4*)&atS[w][t][1][4 * j4];
        float4 a2v = *(const float4*)&atS[w][t][2][4 * j4];
        float4 a3v = *(const float4*)&atS[w][t][3][4 * j4];
        float h;
        h = fmaxf(0.f, fmaf(px.x - pix[t], wx, fmaf(py.x - piy[t], wy, bb)));
        wh[t][0] = fmaf(a0v.x, h, wh[t][0]); wh[t][1] = fmaf(a1v.x, h, wh[t][1]);
        wh[t][2] = fmaf(a2v.x, h, wh[t][2]); wh[t][3] = fmaf(a3v.x, h, wh[t][3]);
        h = fmaxf(0.f, fmaf(px.y - pix[t], wx, fmaf(py.y - piy[t], wy, bb)));
        wh[t][0] = fmaf(a0v.y, h, wh[t][0]); wh[t][1] = fmaf(a1v.y, h, wh[t][1]);
        wh[t][2] = fmaf(a2v.y, h, wh[t][2]); wh[t][3] = fmaf(a3v.y, h, wh[t][3]);
        h = fmaxf(0.f, fmaf(px.z - pix[t], wx, fmaf(py.z - piy[t], wy, bb)));
        wh[t][0] = fmaf(a0v.z, h, wh[t][0]); wh[t][1] = fmaf(a1v.z, h, wh[t][1]);
        wh[t][2] = fmaf(a2v.z, h, wh[t][2]); wh[t][3] = fmaf(a3v.z, h, wh[t][3]);
        h = fmaxf(0.f, fmaf(px.w - pix[t], wx, fmaf(py.w - piy[t], wy, bb)));
        wh[t][0] = fmaf(a0v.w, h, wh[t][0]); wh[t][1] = fmaf(a1v.w, h, wh[t][1]);
        wh[t][2] = fmaf(a2v.w, h, wh[t][2]); wh[t][3] = fmaf(a3v.w, h, wh[t][3]);
      }
    }
    #pragma unroll
    for (int t = 0; t < 4; ++t)
      #pragma unroll
      for (int hd = 0; hd < 4; ++hd) qwhS[w][t][hd][l] = wh[t][hd];
  }
  wsync();

  // S7: ctx (vb + v2p in registers; owA issued here; R14 FMA order, W2v
  // values bf16 via bl/bh of v2p)
  uint4 owA[16];
  {
    #pragma unroll
    for (int m8 = 0; m8 < 8; ++m8) {
      owA[2 * m8]     = W4o[c0 * 16 + m8];
      owA[2 * m8 + 1] = W4o[(c0 + 1) * 16 + m8];
    }
  }
  {
    const int hd = l >> 4;
    float cx0[4] = {0,0,0,0}, cx1[4] = {0,0,0,0};
    #pragma unroll
    for (int n4 = 0; n4 < 16; ++n4) {
      uint4 gq = v2p[n4];      // rows 4n4..4n4+3 of W2v, lane's channel pair
      u32 v0 = vb[4 * n4 + 0];
      u32 v1 = vb[4 * n4 + 1];
      u32 v2 = vb[4 * n4 + 2];
      u32 v3 = vb[4 * n4 + 3];
      #pragma unroll
      for (int t = 0; t < 4; ++t) {
        float4 whv = *(const float4*)&qwhS[w][t][hd][4 * n4];
        float4 atv = *(const float4*)&atS[w][t][hd][4 * n4];
        float a0 = cx0[t], a1 = cx1[t];
        a0 = fmaf(whv.x, bl(gq.x), a0); a1 = fmaf(whv.x, bh(gq.x), a1);
        a0 = fmaf(atv.x, bl(v0), a0);   a1 = fmaf(atv.x, bh(v0), a1);
        a0 = fmaf(whv.y, bl(gq.y), a0); a1 = fmaf(whv.y, bh(gq.y), a1);
        a0 = fmaf(atv.y, bl(v1), a0);   a1 = fmaf(atv.y, bh(v1), a1);
        a0 = fmaf(whv.z, bl(gq.z), a0); a1 = fmaf(whv.z, bh(gq.z), a1);
        a0 = fmaf(atv.z, bl(v2), a0);   a1 = fmaf(atv.z, bh(v2), a1);
        a0 = fmaf(whv.w, bl(gq.w), a0); a1 = fmaf(whv.w, bh(gq.w), a1);
        a0 = fmaf(atv.w, bl(v3), a0);   a1 = fmaf(atv.w, bh(v3), a1);
        cx0[t] = a0; cx1[t] = a1;
      }
    }
    wsync();
    #pragma unroll
    for (int t = 0; t < 4; ++t)
      qSu[w][t][l] = pk(cx0[t], cx1[t]);             // ctx over q (packed)
  }
  wsync();

  // S8: attn_out = out_w @ ctx + out_b  (owA staged; owB + PWB-Q0 here)
  uint4 pf0[8], pg0[8];          // PWB quarter Q0 (m8 0..3), consumed in S9
  {
    float2 b = ((const float2*)ob)[l];
    float a0[4], a1[4];
    #pragma unroll
    for (int t = 0; t < 4; ++t) { a0[t] = b.x; a1[t] = b.y; }
    uint4 owB[16];
    #pragma unroll
    for (int m8 = 8; m8 < 16; ++m8) {
      owB[2 * (m8 - 8)]     = W4o[c0 * 16 + m8];
      owB[2 * (m8 - 8) + 1] = W4o[(c0 + 1) * 16 + m8];
    }
    #pragma unroll
    for (int m8 = 0; m8 < 8; ++m8) {
      #pragma unroll
      for (int t = 0; t < 4; ++t) {
        uint4 cp = *(const uint4*)&qSu[w][t][4 * m8];
        a0[t] = dot8b(owA[2 * m8],     cp, a0[t]);
        a1[t] = dot8b(owA[2 * m8 + 1], cp, a1[t]);
      }
    }
    #pragma unroll
    for (int k = 0; k < 4; ++k) {
      pf0[2 * k]     = W4p[c0 * 32 + k];
      pf0[2 * k + 1] = W4p[(c0 + 1) * 32 + k];
      pg0[2 * k]     = W4p[c0 * 32 + 16 + k];
      pg0[2 * k + 1] = W4p[(c0 + 1) * 32 + 16 + k];
    }
    #pragma unroll
    for (int m8 = 8; m8 < 16; ++m8) {
      #pragma unroll
      for (int t = 0; t < 4; ++t) {
        uint4 cp = *(const uint4*)&qSu[w][t][4 * m8];
        a0[t] = dot8b(owB[2 * (m8 - 8)],     cp, a0[t]);
        a1[t] = dot8b(owB[2 * (m8 - 8) + 1], cp, a1[t]);
      }
    }
    wsync();   // qwhS (wh) reads in S7 complete before overwrite
    #pragma unroll
    for (int t = 0; t < 4; ++t)
      ((u32*)&qwhS[w][t][0][0])[l] = pk(a0[t], a1[t]);
  }
  wsync();

  // S9: out = proj_w @ [feats; attn_out] + proj_b  (fp32 out)
  // Quartered: consume Qk while issuing Q(k+1). Per-m8 order ua,ub,uc,ud
  // with t inner — EXACTLY R11's sequence -> bit-identical accumulation.
  {
    float2 b = ((const float2*)pb)[l];
    float a0[4], a1[4];
    #pragma unroll
    for (int t = 0; t < 4; ++t) { a0[t] = b.x; a1[t] = b.y; }

    uint4 pf1[8], pg1[8];        // Q1 (m8 4..7)
    #pragma unroll
    for (int k = 0; k < 4; ++k) {
      pf1[2 * k]     = W4p[c0 * 32 + 4 + k];
      pf1[2 * k + 1] = W4p[(c0 + 1) * 32 + 4 + k];
      pg1[2 * k]     = W4p[c0 * 32 + 16 + 4 + k];
      pg1[2 * k + 1] = W4p[(c0 + 1) * 32 + 16 + 4 + k];
    }
    #pragma unroll
    for (int m8 = 0; m8 < 4; ++m8) {       // consume Q0
      #pragma unroll
      for (int t = 0; t < 4; ++t) {
        uint4 fp = *(const uint4*)&fqSu[w][t][4 * m8];
        uint4 gp = *(const uint4*)((const u32*)&qwhS[w][t][0][0] + 4 * m8);
        a0[t] = dot8b(pf0[2 * m8],     fp, a0[t]);
        a1[t] = dot8b(pf0[2 * m8 + 1], fp, a1[t]);
        a0[t] = dot8b(pg0[2 * m8],     gp, a0[t]);
        a1[t] = dot8b(pg0[2 * m8 + 1], gp, a1[t]);
      }
    }
    uint4 pf2[8], pg2[8];        // Q2 (m8 8..11)
    #pragma unroll
    for (int k = 0; k < 4; ++k) {
      pf2[2 * k]     = W4p[c0 * 32 + 8 + k];
      pf2[2 * k + 1] = W4p[(c0 + 1) * 32 + 8 + k];
      pg2[2 * k]     = W4p[c0 * 32 + 16 + 8 + k];
      pg2[2 * k + 1] = W4p[(c0 + 1) * 32 + 16 + 8 + k];
    }
    #pragma unroll
    for (int m8 = 4; m8 < 8; ++m8) {       // consume Q1
      #pragma unroll
      for (int t = 0; t < 4; ++t) {
        uint4 fp = *(const uint4*)&fqSu[w][t][4 * m8];
        uint4 gp = *(const uint4*)((const u32*)&qwhS[w][t][0][0] + 4 * m8);
        a0[t] = dot8b(pf1[2 * (m8 - 4)],     fp, a0[t]);
        a1[t] = dot8b(pf1[2 * (m8 - 4) + 1], fp, a1[t]);
        a0[t] = dot8b(pg1[2 * (m8 - 4)],     gp, a0[t]);
        a1[t] = dot8b(pg1[2 * (m8 - 4) + 1], gp, a1[t]);
      }
    }
    uint4 pf3[8], pg3[8];        // Q3 (m8 12..15)
    #pragma unroll
    for (int k = 0; k < 4; ++k) {
      pf3[2 * k]     = W4p[c0 * 32 + 12 + k];
      pf3[2 * k + 1] = W4p[(c0 + 1) * 32 + 12 + k];
      pg3[2 * k]     = W4p[c0 * 32 + 16 + 12 + k];
      pg3[2 * k + 1] = W4p[(c0 + 1) * 32 + 16 + 12 + k];
    }
    #pragma unroll
    for (int m8 = 8; m8 < 12; ++m8) {      // consume Q2
      #pragma unroll
      for (int t = 0; t < 4; ++t) {
        uint4 fp = *(const uint4*)&fqSu[w][t][4 * m8];
        uint4 gp = *(const uint4*)((const u32*)&qwhS[w][t][0][0] + 4 * m8);
        a0[t] = dot8b(pf2[2 * (m8 - 8)],     fp, a0[t]);
        a1[t] = dot8b(pf2[2 * (m8 - 8) + 1], fp, a1[t]);
        a0[t] = dot8b(pg2[2 * (m8 - 8)],     gp, a0[t]);
        a1[t] = dot8b(pg2[2 * (m8 - 8) + 1], gp, a1[t]);
      }
    }
    #pragma unroll
    for (int m8 = 12; m8 < 16; ++m8) {     // consume Q3
      #pragma unroll
      for (int t = 0; t < 4; ++t) {
        uint4 fp = *(const uint4*)&fqSu[w][t][4 * m8];
        uint4 gp = *(const uint4*)((const u32*)&qwhS[w][t][0][0] + 4 * m8);
        a0[t] = dot8b(pf3[2 * (m8 - 12)],     fp, a0[t]);
        a1[t] = dot8b(pf3[2 * (m8 - 12) + 1], fp, a1[t]);
        a0[t] = dot8b(pg3[2 * (m8 - 12)],     gp, a0[t]);
        a1[t] = dot8b(pg3[2 * (m8 - 12) + 1], gp, a1[t]);
      }
    }
    #pragma unroll
    for (int t = 0; t < 4; ++t)
      ((float2*)outp)[ig[t] * 64 + l] = make_float2(a0[t], a1[t]);
  }
}

extern "C" void kernel_launch(void* const* d_in, const int* in_sizes, int n_in,
                              void* d_out, int out_size, void* d_ws, size_t ws_size,
                              hipStream_t stream) {
  (void)in_sizes; (void)n_in; (void)out_size; (void)ws_size;
  const float* nf  = (const float*)d_in[0];
  const float* pos = (const float*)d_in[1];
  const float* w1  = (const float*)d_in[2];
  const float* b1  = (const float*)d_in[3];
  const float* w2  = (const float*)d_in[4];
  const float* b2  = (const float*)d_in[5];
  const float* ipw = (const float*)d_in[6];
  const float* ipb = (const float*)d_in[7];
  const float* ow  = (const float*)d_in[8];
  const float* ob  = (const float*)d_in[9];
  const float* pw  = (const float*)d_in[10];
  const float* pb  = (const float*)d_in[11];

  char* ws = (char*)d_ws;
  u32* W2KB = (u32*)(ws);
  u32* W2VB = (u32*)(ws + (32 << 10));
  u32* WQB  = (u32*)(ws + (64 << 10));
  u32* OWB  = (u32*)(ws + (96 << 10));
  u32* PWB  = (u32*)(ws + (128 << 10));
  u32* KBt  = (u32*)(ws + (192 << 10));
  u32* VB   = (u32*)(ws + (192 << 10) + (128 * 4096 * 4));

  ee_setup<<<dim3(552), dim3(256), 0, stream>>>(nf, b2, ipw, ipb, w2, ow, pw,
                                                W2KB, W2VB, WQB, OWB, PWB, KBt, VB);
  ee_main<<<dim3(512), dim3(256), 0, stream>>>(nf, pos, w1, b1, ipb, ob, pb,
                                               W2KB, W2VB, WQB, OWB, PWB,
                                               KBt, VB, (float*)d_out);
}